// Round 7
// baseline (497.802 us; speedup 1.0000x reference)
//
#include <hip/hip_runtime.h>
#include <hip/hip_bf16.h>
#include <math.h>

#define TPB  256     // main
#define RTPB 128     // rescue
#define EPS_GAP 1e-4f
#define LTAB 13440   // 240*56 fused [lemb0|bcp] table (floats) -- rescue only
#define LDSZ 13680   // + 240 bcx                               -- rescue only

typedef unsigned int u32;
typedef unsigned long long u64;
typedef __attribute__((ext_vector_type(8))) short bf16x8;
typedef __attribute__((ext_vector_type(4))) float f32x4;

// ============ analytic fp32 scan: O(8) per level =============================
__device__ __forceinline__ int scan_fast(const float* x, float scale,
                                         float* residual, bool protect, bool& flag){
    float aa[8]; int neg=0; float S=0.f;
    #pragma unroll
    for (int k=0;k<8;k++){
        float v=x[k]; float av=fabsf(v);
        aa[k]=av; S+=av; neg |= (v<0.f)?(1<<k):0;
    }
    float t1=-1e30f,t2=-1e30f,t3=-1e30f; int p1=0,p2=0;
    #pragma unroll
    for (int k=0;k<8;k++){
        float v=aa[k];
        bool g1=v>t1, g2=v>t2, g3=v>t3;
        t3 = g2 ? t2 : (g3 ? v : t3);
        t2 = g1 ? t1 : (g2 ? v : t2);
        p2 = g1 ? p1 : (g2 ? k : p2);
        t1 = g1 ? v : t1;
        p1 = g1 ? k : p1;
    }
    float n1=1e30f,n2v=1e30f; int m1=0;
    #pragma unroll
    for (int k=0;k<8;k++){
        float v=aa[k];
        bool l1=v<n1, l2=v<n2v;
        n2v = l1 ? n1 : (l2 ? v : n2v);
        n1  = l1 ? v : n1;
        m1  = l1 ? k : m1;
    }
    int bi = min(p1,p2), bj = max(p1,p2);
    float pv = 2.f*(t1+t2), pr = 2.f*(t1+t3);
    int par = __builtin_popcount((unsigned)neg)&1;
    float hv, hr; int hb;
    if (par==0){ hv=S;          hb=neg;           hr=S-2.f*(n1+n2v); }
    else       { hv=S-2.f*n1;   hb=neg^(1<<m1);   hr=S-2.f*n2v; }
    bool pair = (pv >= hv);
    float best = pair? pv: hv, alt = pair? hv: pv;
    float second = fmaxf(alt, fmaxf(pr,hr));
    if (protect) flag = flag || ((best-second) < EPS_GAP);
    int s = (((neg>>bi)&1)<<1) | ((neg>>bj)&1);
    int pidx = 4*(7*bi - ((bi*(bi-1))>>1) + (bj-bi-1)) + s;
    int hidx = 112 + (hb>>1);
    float sI = ((neg>>bi)&1)? scale : -scale;
    float sJ = ((neg>>bj)&1)? scale : -scale;
    #pragma unroll
    for (int k=0;k<8;k++){
        float cp = ((k==bi)? sI:0.f) + ((k==bj)? sJ:0.f);
        float ch = ((hb>>k)&1)? 0.5f*scale : -0.5f*scale;
        residual[k] += (pair? cp : ch);
    }
    return pair? pidx : hidx;
}

// ============ analytic f64 scan (rescue) ======================================
__device__ __forceinline__ int scan_fast_f64(const double* x, double scale,
                                             double* residual){
    double aa[8]; int neg=0; double S=0.0;
    #pragma unroll
    for (int k=0;k<8;k++){
        double v=x[k]; double av=fabs(v);
        aa[k]=av; S+=av; neg |= (v<0.0)?(1<<k):0;
    }
    double t1=-1e300,t2=-1e300; int p1=0,p2=0;
    #pragma unroll
    for (int k=0;k<8;k++){
        double v=aa[k];
        bool g1=v>t1, g2=v>t2;
        t2 = g1 ? t1 : (g2 ? v : t2);
        p2 = g1 ? p1 : (g2 ? k : p2);
        t1 = g1 ? v : t1;
        p1 = g1 ? k : p1;
    }
    double n1=1e300; int m1=0;
    #pragma unroll
    for (int k=0;k<8;k++){
        double v=aa[k];
        bool l1=v<n1;
        n1 = l1 ? v : n1;
        m1 = l1 ? k : m1;
    }
    int bi = min(p1,p2), bj = max(p1,p2);
    double pv = 2.0*(t1+t2);
    int par = __builtin_popcount((unsigned)neg)&1;
    double hv; int hb;
    if (par==0){ hv=S;          hb=neg; }
    else       { hv=S-2.0*n1;   hb=neg^(1<<m1); }
    bool pair = (pv >= hv);
    int s = (((neg>>bi)&1)<<1) | ((neg>>bj)&1);
    int pidx = 4*(7*bi - ((bi*(bi-1))>>1) + (bj-bi-1)) + s;
    int hidx = 112 + (hb>>1);
    double sI = ((neg>>bi)&1)? scale : -scale;
    double sJ = ((neg>>bj)&1)? scale : -scale;
    #pragma unroll
    for (int k=0;k<8;k++){
        double cp = ((k==bi)? sI:0.0) + ((k==bj)? sJ:0.0);
        double ch = ((hb>>k)&1)? 0.5*scale : -0.5*scale;
        residual[k] += (pair? cp : ch);
    }
    return pair? pidx : hidx;
}

// stage refine weights: [0..2703]=W1, [2704..5407]=W2T[k][m], [5408..5511]=Bv
__device__ __forceinline__ void stageRW(float* RW, int tid, int tpb,
    const float* __restrict__ rw1, const float* __restrict__ rw2,
    const float* __restrict__ rb1, const float* __restrict__ rb2)
{
    for (int t = tid; t < 2704; t += tpb) RW[t] = rw1[t];
    for (int t = tid; t < 2704; t += tpb){
        int m = t/52, k = t - m*52;
        RW[2704 + k*52 + m] = rw2[t];
    }
    for (int t = tid; t < 104; t += tpb) RW[5408+t] = (t < 52) ? rb1[t] : rb2[t-52];
}

// ============ scalar phase B + fused refine (RESCUE ONLY) =====================
__device__ __forceinline__ void phaseB(const float* __restrict__ L, float* T,
    const float* qf,
    int i1,int i2,int i3,int i4,int i5,int i6,int i7, float decay,
    const float* __restrict__ lemb, const float* __restrict__ rcpar,
    const float* __restrict__ RW, float sg,
    float* __restrict__ orow)
{
    const float IS2 = 0.70710678118654752f;
    const float HS2 = 0.35355339059327376f;
    const float LG2 = 0.69314718055994531f;
    float hi16[16];
    {
        float a01p=qf[0]+qf[1], a01m=qf[0]-qf[1];
        float a23p=qf[2]+qf[3], a23m=qf[2]-qf[3];
        float a45p=qf[4]+qf[5], a45m=qf[4]-qf[5];
        float a67p=qf[6]+qf[7], a67m=qf[6]-qf[7];
        float s01[4]={a01p,-a01m,a01m,-a01p};
        float s23[4]={a23p,-a23m,a23m,-a23p};
        float s45[4]={a45p,-a45m,a45m,-a45p};
        float s67[4]={a67p,-a67m,a67m,-a67p};
        #pragma unroll
        for (int p=0;p<16;p++){ T[8+p]=s01[p&3]+s23[(p>>2)&3]; hi16[p]=s45[p&3]+s67[(p>>2)&3]; }
        #pragma unroll
        for (int k=0;k<8;k++) T[k]=qf[k];
    }
    float emb[56], den=0.f;
    #pragma unroll
    for (int k=0;k<56;k++) emb[k]=0.f;

    auto proc = [&](float sims, int j){
        float e = __expf(sims - L[LTAB + j]*LG2);
        den += e;
        const float4* Lr = (const float4*)(L + j*56);
        #pragma unroll
        for (int t=0;t<14;t++){
            float4 v = Lr[t];
            emb[4*t+0]=fmaf(e,v.x,emb[4*t+0]); emb[4*t+1]=fmaf(e,v.y,emb[4*t+1]);
            emb[4*t+2]=fmaf(e,v.z,emb[4*t+2]); emb[4*t+3]=fmaf(e,v.w,emb[4*t+3]);
        }
    };
    #pragma unroll
    for (int h=0;h<16;h++){
        float hv = hi16[h];
        int ph = __builtin_popcount(h)&1;
        #pragma unroll 1
        for (int m=0;m<8;m++){
            int lo = (m<<1) | ((__builtin_popcount(m)&1)^ph);
            proc((T[8+lo]+hv)*HS2, 112 + (h<<3) + m);
        }
    }
    {
        int ii=0, jn=1;
        #pragma unroll 1
        for (int pc=0;pc<28;++pc){
            float a=T[ii], b=T[jn];
            float p=a+b, mm=a-b;
            proc( p*IS2, 4*pc+0);
            proc( mm*IS2,4*pc+1);
            proc(-mm*IS2,4*pc+2);
            proc(-p*IS2, 4*pc+3);
            if (++jn==8){ ++ii; jn=ii+1; }
        }
    }
    float rden = 1.f/den;
    #pragma unroll
    for (int k=0;k<56;k++) emb[k] *= rden;

    {
        float dp = decay;
        #define DO_G(LVL, IV) { \
            float ild = 1.0f/dp; \
            const float4* ep4 = (const float4*)(lemb + ((size_t)(LVL)*240 + (size_t)(IV))*52); \
            _Pragma("unroll") for (int t4=0;t4<13;t4++){ float4 v=ep4[t4]; \
                emb[4*t4+0]=fmaf(ild,v.x,emb[4*t4+0]); emb[4*t4+1]=fmaf(ild,v.y,emb[4*t4+1]); \
                emb[4*t4+2]=fmaf(ild,v.z,emb[4*t4+2]); emb[4*t4+3]=fmaf(ild,v.w,emb[4*t4+3]); } \
            float4 cv = *(const float4*)(rcpar + ((size_t)((LVL)-1)*240 + (size_t)(IV))*4); \
            emb[52]=fmaf(ild,cv.x,emb[52]); emb[53]=fmaf(ild,cv.y,emb[53]); \
            emb[54]=fmaf(ild,cv.z,emb[54]); emb[55]=fmaf(ild,cv.w,emb[55]); \
            dp *= decay; }
        DO_G(1,i1) DO_G(2,i2) DO_G(3,i3) DO_G(4,i4) DO_G(5,i5) DO_G(6,i6) DO_G(7,i7)
        #undef DO_G
    }

    // fused gated refinement (identical math/order to standalone K3)
    float racc[52];
    #pragma unroll
    for (int m=0;m<52;m++) racc[m]=0.f;
    #pragma unroll 1
    for (int k=0;k<52;k++){
        const float4* w1 = (const float4*)(RW + k*52);
        float a0=0.f,a1=0.f,a2=0.f,a3=0.f;
        #pragma unroll
        for (int t=0;t<13;t++){
            float4 w = w1[t];
            a0=fmaf(w.x,emb[4*t+0],a0); a1=fmaf(w.y,emb[4*t+1],a1);
            a2=fmaf(w.z,emb[4*t+2],a2); a3=fmaf(w.w,emb[4*t+3],a3);
        }
        float a = ((a0+a1)+(a2+a3)) + RW[5408+k];
        float gk = sg*0.5f*a*(1.f+erff(a*0.70710678f));
        const float4* w2 = (const float4*)(RW + 2704 + k*52);
        #pragma unroll
        for (int t=0;t<13;t++){
            float4 w = w2[t];
            racc[4*t+0]=fmaf(gk,w.x,racc[4*t+0]); racc[4*t+1]=fmaf(gk,w.y,racc[4*t+1]);
            racc[4*t+2]=fmaf(gk,w.z,racc[4*t+2]); racc[4*t+3]=fmaf(gk,w.w,racc[4*t+3]);
        }
    }

    float4* o4 = (float4*)orow;
    #pragma unroll
    for (int t=0;t<13;t++){
        float4 v;
        v.x = emb[4*t+0] + fmaf(sg, RW[5460+4*t+0], racc[4*t+0]);
        v.y = emb[4*t+1] + fmaf(sg, RW[5460+4*t+1], racc[4*t+1]);
        v.z = emb[4*t+2] + fmaf(sg, RW[5460+4*t+2], racc[4*t+2]);
        v.w = emb[4*t+3] + fmaf(sg, RW[5460+4*t+3], racc[4*t+3]);
        o4[t] = v;
    }
    o4[13] = make_float4(emb[52], emb[53], emb[54], emb[55]);
}

__device__ __forceinline__ void stageL(float* L, int tid, int tpb,
    const float* __restrict__ lemb, const float* __restrict__ bcp,
    const float* __restrict__ bcx)
{
    for (int t = tid; t < LTAB; t += tpb){
        int j = t/56, c = t - j*56;
        L[t] = (c < 52) ? lemb[j*52 + c] : bcp[j*4 + (c-52)];
    }
    for (int t = tid; t < 240; t += tpb) L[LTAB + t] = bcx[t];
}

// ============ helpers for MFMA main ==========================================
__device__ __forceinline__ unsigned short f2bf(float x){
    union{float f; u32 u;} c; c.f = x;
    u32 u = c.u + 0x7fffu + ((c.u>>16)&1u);
    return (unsigned short)(u>>16);
}
__device__ __forceinline__ u32 pk2(float a, float b){
    union { __hip_bfloat162 h; u32 u; } cv;
    cv.h = __float22bfloat162_rn(make_float2(a,b));
    return cv.u;
}

#define BT_PITCH 264
#define E_PITCH  260
#define SCR_PITCH 68

#define EP4(i,jn,J,W) { \
    float P=(qf[i]+qf[jn])*IS2, M=(qf[i]-qf[jn])*IS2; \
    float e0=__expf(fmaf(-LG2,bcxL[(J)+0],P)); \
    float e1=__expf(fmaf(-LG2,bcxL[(J)+1],M)); \
    float e2=__expf(fmaf(-LG2,bcxL[(J)+2],-M)); \
    float e3=__expf(fmaf(-LG2,bcxL[(J)+3],-P)); \
    den += ((e0+e1)+(e2+e3)); \
    ESH[((W)+0)*E_PITCH + tid]=pk2(e0,e1); \
    ESH[((W)+1)*E_PITCH + tid]=pk2(e2,e3); }

#define EH8(h,J,W,L0,L1,L2,L3,L4,L5,L6,L7) { \
    float hv=hi16[h]; \
    float e0=__expf(fmaf(-LG2,bcxL[(J)+0],(lo16[L0]+hv)*HS2)); \
    float e1=__expf(fmaf(-LG2,bcxL[(J)+1],(lo16[L1]+hv)*HS2)); \
    float e2=__expf(fmaf(-LG2,bcxL[(J)+2],(lo16[L2]+hv)*HS2)); \
    float e3=__expf(fmaf(-LG2,bcxL[(J)+3],(lo16[L3]+hv)*HS2)); \
    float e4=__expf(fmaf(-LG2,bcxL[(J)+4],(lo16[L4]+hv)*HS2)); \
    float e5=__expf(fmaf(-LG2,bcxL[(J)+5],(lo16[L5]+hv)*HS2)); \
    float e6=__expf(fmaf(-LG2,bcxL[(J)+6],(lo16[L6]+hv)*HS2)); \
    float e7=__expf(fmaf(-LG2,bcxL[(J)+7],(lo16[L7]+hv)*HS2)); \
    den += (((e0+e1)+(e2+e3))+((e4+e5)+(e6+e7))); \
    ESH[((W)+0)*E_PITCH + tid]=pk2(e0,e1); \
    ESH[((W)+1)*E_PITCH + tid]=pk2(e2,e3); \
    ESH[((W)+2)*E_PITCH + tid]=pk2(e4,e5); \
    ESH[((W)+3)*E_PITCH + tid]=pk2(e6,e7); }

#define EFLUSH(c) { \
    union { u32 u[4]; bf16x8 v; } Af; \
    const unsigned short* bp = BtT + pp*BT_PITCH + qq*8 + (c)*32; \
    bf16x8 b0 = *(const bf16x8*)(const void*)(bp); \
    bf16x8 b1 = *(const bf16x8*)(const void*)(bp + 16*BT_PITCH); \
    bf16x8 b2 = *(const bf16x8*)(const void*)(bp + 32*BT_PITCH); \
    bf16x8 b3 = *(const bf16x8*)(const void*)(bp + 48*BT_PITCH); \
    _Pragma("unroll") for (int s4=0;s4<4;s4++){ \
        const u32* ep = ESH + (4*qq)*E_PITCH + wbase + 16*s4 + pp; \
        Af.u[0]=ep[0]; Af.u[1]=ep[E_PITCH]; Af.u[2]=ep[2*E_PITCH]; Af.u[3]=ep[3*E_PITCH]; \
        acc[s4][0]=__builtin_amdgcn_mfma_f32_16x16x32_bf16(Af.v,b0,acc[s4][0],0,0,0); \
        acc[s4][1]=__builtin_amdgcn_mfma_f32_16x16x32_bf16(Af.v,b1,acc[s4][1],0,0,0); \
        acc[s4][2]=__builtin_amdgcn_mfma_f32_16x16x32_bf16(Af.v,b2,acc[s4][2],0,0,0); \
        acc[s4][3]=__builtin_amdgcn_mfma_f32_16x16x32_bf16(Af.v,b3,acc[s4][3],0,0,0); \
    } }

// ============ K1: fused fp32 A + MFMA softmax-GEMM B + refine ================
// No min-waves hint (R2/R4: hint => arch-VGPR cap + 120-220 MB scratch spill).
// LDS 74.3 KB: reg-bound at 1 block/CU anyway, so dedicated refine-W region is free.
__global__ __launch_bounds__(TPB) void e8_main(
    const float* __restrict__ g_obs,
    const float* __restrict__ pw1, const float* __restrict__ pb1,
    const float* __restrict__ pw2, const float* __restrict__ pb2,
    const float* __restrict__ lemb, const float* __restrict__ bcp,
    const float* __restrict__ rcpar, const float* __restrict__ bcx,
    const float* __restrict__ glogdecay,
    const float* __restrict__ rw1, const float* __restrict__ rb1,
    const float* __restrict__ rw2, const float* __restrict__ rb2,
    const float* __restrict__ rgate,
    u32* __restrict__ cnt, u32* __restrict__ list,
    unsigned char* __restrict__ flags, int useCompact,
    float* __restrict__ out, int B)
{
    const float IS2 = 0.70710678118654752f;
    const float HS2 = 0.35355339059327376f;
    const float LG2 = 0.69314718055994531f;

    __shared__ __align__(16) unsigned short BtT[64*BT_PITCH]; // 33792 B bf16 L^T
    __shared__ __align__(16) char UN[17408];                  // obs / E / scratch union
    __shared__ float bcxL[240];
    __shared__ __align__(16) float RWs[5512];                 // refine weights (dedicated)
    u32*   ESH  = (u32*)UN;
    float* scrF = (float*)UN;
    float* obsF = (float*)UN;

    const int tid  = threadIdx.x;
    const int row  = blockIdx.x*TPB + tid;
    const bool active = row < B;
    const int lane = tid & 63;
    const int qq = lane >> 4, pp = lane & 15;
    const int wbase = tid & 192;       // wave index * 64

    // ---- staging: Bt (coalesced linear reads + LDS transpose writes), bcx,
    //      refine weights, obs ----
    for (int t = tid; t < 2048; t += TPB)          // cols 56..63, all k
        BtT[(56 + (t>>8))*BT_PITCH + (t&255)] = 0;
    for (int t = tid; t < 1024; t += TPB)          // all cols, k 240..255
        BtT[(t>>4)*BT_PITCH + 240 + (t&15)] = 0;
    for (int t = tid; t < 12480; t += TPB){        // lemb0: linear
        int k = t/52, c = t - k*52;
        BtT[c*BT_PITCH + k] = f2bf(lemb[t]);
    }
    for (int t = tid; t < 960; t += TPB){          // bcp: linear
        int k = t>>2, c = 52 + (t&3);
        BtT[c*BT_PITCH + k] = f2bf(bcp[t]);
    }
    for (int t = tid; t < 240; t += TPB) bcxL[t] = bcx[t];
    stageRW(RWs, tid, TPB, rw1, rw2, rb1, rb2);
    {
        const size_t base = (size_t)blockIdx.x*TPB*14;
        const size_t lim  = (size_t)B*14;
        for (int t = tid; t < TPB*14; t += TPB){
            size_t g = base + (size_t)t;
            float v = (g < lim) ? g_obs[g] : 0.f;
            int r = t/14, c = t - r*14;
            obsF[r*17 + c] = v;
        }
    }
    __syncthreads();

    // ---- phase A: MLP -> q, analytic residual scan (fp32) ----
    float qf[8];
    int idxs[8] = {0,0,0,0,0,0,0,0};
    float decay = 1.f;
    bool flag = false;
    {
        float ob[14];
        #pragma unroll
        for (int j=0;j<14;j++) ob[j]=obsF[tid*17+j];
        float qa[8];
        #pragma unroll
        for (int m=0;m<8;m++) qa[m]=pb2[m];
        #pragma unroll 1
        for (int k=0;k<32;k++){
            float a = pb1[k];
            #pragma unroll
            for (int j=0;j<14;j++) a = fmaf(pw1[k*14+j], ob[j], a);
            float h = 0.5f*a*(1.f+erff(a*0.70710678f));
            #pragma unroll
            for (int m=0;m<8;m++) qa[m] = fmaf(pw2[m*32+k], h, qa[m]);
        }
        float n2=0.f;
        #pragma unroll
        for (int m=0;m<8;m++) n2 = fmaf(qa[m],qa[m],n2);
        float nr = fmaxf(sqrtf(n2), 1e-12f);
        float sc = 1.41421356237309505f/nr;
        float residual[8];
        #pragma unroll
        for (int m=0;m<8;m++){ qf[m]=qa[m]*sc; residual[m]=qf[m]; }

        decay = expf(glogdecay[0]);
        float dpow = 1.f;
        #pragma unroll
        for (int lvl=0; lvl<8; ++lvl){
            float rs = 0.5f*dpow;
            float x[8];
            #pragma unroll
            for (int k=0;k<8;k++) x[k]=residual[k]*rs;
            idxs[lvl] = scan_fast(x, 2.f/dpow, residual, (lvl<3), flag);
            dpow *= decay;
        }
    }
    flag = flag && active;

    if (useCompact){
        u64 mask = __ballot(flag);
        if (mask){
            int leader = __builtin_ctzll(mask);
            u32 base = 0;
            if (lane == leader) base = atomicAdd(cnt, (u32)__builtin_popcountll(mask));
            base = __shfl(base, leader, 64);
            if (flag){
                u32 pos = (u32)__builtin_popcountll(mask & ((1ull<<lane)-1ull));
                list[base+pos] = (u32)row;
            }
        }
    } else if (active){
        flags[row] = flag ? 1 : 0;
    }

    __syncthreads();   // obs region done -> reusable as E

    // ---- Hadamard tables ----
    float lo16[16], hi16[16];
    {
        float a01p=qf[0]+qf[1], a01m=qf[0]-qf[1];
        float a23p=qf[2]+qf[3], a23m=qf[2]-qf[3];
        float a45p=qf[4]+qf[5], a45m=qf[4]-qf[5];
        float a67p=qf[6]+qf[7], a67m=qf[6]-qf[7];
        float s01[4]={a01p,-a01m,a01m,-a01p};
        float s23[4]={a23p,-a23m,a23m,-a23p};
        float s45[4]={a45p,-a45m,a45m,-a45p};
        float s67[4]={a67p,-a67m,a67m,-a67p};
        #pragma unroll
        for (int p=0;p<16;p++){ lo16[p]=s01[p&3]+s23[p>>2]; hi16[p]=s45[p&3]+s67[p>>2]; }
    }

    // ---- chunked softmax-GEMM: E[64,240] x L[240,64] on MFMA ----
    f32x4 acc[4][4];
    #pragma unroll
    for (int s=0;s<4;s++)
        #pragma unroll
        for (int n=0;n<4;n++)
            acc[s][n] = f32x4{0.f,0.f,0.f,0.f};
    float den = 0.f;

    EP4(0,1,  0, 0) EP4(0,2,  4, 2) EP4(0,3,  8, 4) EP4(0,4, 12, 6)
    EP4(0,5, 16, 8) EP4(0,6, 20,10) EP4(0,7, 24,12) EP4(1,2, 28,14)
    EFLUSH(0)
    EP4(1,3, 32, 0) EP4(1,4, 36, 2) EP4(1,5, 40, 4) EP4(1,6, 44, 6)
    EP4(1,7, 48, 8) EP4(2,3, 52,10) EP4(2,4, 56,12) EP4(2,5, 60,14)
    EFLUSH(1)
    EP4(2,6, 64, 0) EP4(2,7, 68, 2) EP4(3,4, 72, 4) EP4(3,5, 76, 6)
    EP4(3,6, 80, 8) EP4(3,7, 84,10) EP4(4,5, 88,12) EP4(4,6, 92,14)
    EFLUSH(2)
    EP4(4,7, 96, 0) EP4(5,6,100, 2) EP4(5,7,104, 4) EP4(6,7,108, 6)
    EH8(0,112, 8, 0,3,5,6,9,10,12,15)
    EH8(1,120,12, 1,2,4,7,8,11,13,14)
    EFLUSH(3)
    EH8(2,128, 0, 1,2,4,7,8,11,13,14)
    EH8(3,136, 4, 0,3,5,6,9,10,12,15)
    EH8(4,144, 8, 1,2,4,7,8,11,13,14)
    EH8(5,152,12, 0,3,5,6,9,10,12,15)
    EFLUSH(4)
    EH8(6,160, 0, 0,3,5,6,9,10,12,15)
    EH8(7,168, 4, 1,2,4,7,8,11,13,14)
    EH8(8,176, 8, 1,2,4,7,8,11,13,14)
    EH8(9,184,12, 0,3,5,6,9,10,12,15)
    EFLUSH(5)
    EH8(10,192, 0, 0,3,5,6,9,10,12,15)
    EH8(11,200, 4, 1,2,4,7,8,11,13,14)
    EH8(12,208, 8, 0,3,5,6,9,10,12,15)
    EH8(13,216,12, 1,2,4,7,8,11,13,14)
    EFLUSH(6)
    EH8(14,224, 0, 1,2,4,7,8,11,13,14)
    EH8(15,232, 4, 0,3,5,6,9,10,12,15)
    #pragma unroll
    for (int w2=8; w2<16; w2++) ESH[w2*E_PITCH + tid]=0u;
    EFLUSH(7)

    __syncthreads();   // all waves' E reads done -> region reusable as scratch

    // ---- epilogue: transpose D back via per-wave scratch ----
    float emb[56];
    float* scr = scrF + (tid>>6)*(16*SCR_PITCH);
    #pragma unroll
    for (int s=0;s<4;s++){
        #pragma unroll
        for (int n=0;n<4;n++){
            #pragma unroll
            for (int r=0;r<4;r++)
                scr[(4*qq+r)*SCR_PITCH + 16*n + pp] = acc[s][n][r];
        }
        if ((lane>>4) == s){
            const float4* rp = (const float4*)(scr + pp*SCR_PITCH);
            #pragma unroll
            for (int t=0;t<14;t++){
                float4 v = rp[t];
                emb[4*t]=v.x; emb[4*t+1]=v.y; emb[4*t+2]=v.z; emb[4*t+3]=v.w;
            }
        }
    }

    if (active){
        float rden = 1.f/den;
        #pragma unroll
        for (int k=0;k<56;k++) emb[k] *= rden;

        float dp = decay;
        #define DO_G2(LVL, IV) { \
            float ild = 1.0f/dp; \
            const float4* ep4 = (const float4*)(lemb + ((size_t)(LVL)*240 + (size_t)(IV))*52); \
            _Pragma("unroll") for (int t4=0;t4<13;t4++){ float4 v=ep4[t4]; \
                emb[4*t4+0]=fmaf(ild,v.x,emb[4*t4+0]); emb[4*t4+1]=fmaf(ild,v.y,emb[4*t4+1]); \
                emb[4*t4+2]=fmaf(ild,v.z,emb[4*t4+2]); emb[4*t4+3]=fmaf(ild,v.w,emb[4*t4+3]); } \
            float4 cv = *(const float4*)(rcpar + ((size_t)((LVL)-1)*240 + (size_t)(IV))*4); \
            emb[52]=fmaf(ild,cv.x,emb[52]); emb[53]=fmaf(ild,cv.y,emb[53]); \
            emb[54]=fmaf(ild,cv.z,emb[54]); emb[55]=fmaf(ild,cv.w,emb[55]); \
            dp *= decay; }
        DO_G2(1,idxs[1]) DO_G2(2,idxs[2]) DO_G2(3,idxs[3]) DO_G2(4,idxs[4])
        DO_G2(5,idxs[5]) DO_G2(6,idxs[6]) DO_G2(7,idxs[7])
        #undef DO_G2

        // ---- fused gated refinement (same math/order as standalone K3) ----
        float sg = 1.f/(1.f+__expf(-rgate[0]));
        float racc[52];
        #pragma unroll
        for (int m=0;m<52;m++) racc[m]=0.f;
        #pragma unroll 1
        for (int k=0;k<52;k++){
            const float4* w1 = (const float4*)(RWs + k*52);
            float a0=0.f,a1=0.f,a2=0.f,a3=0.f;
            #pragma unroll
            for (int t=0;t<13;t++){
                float4 w = w1[t];
                a0=fmaf(w.x,emb[4*t+0],a0); a1=fmaf(w.y,emb[4*t+1],a1);
                a2=fmaf(w.z,emb[4*t+2],a2); a3=fmaf(w.w,emb[4*t+3],a3);
            }
            float a = ((a0+a1)+(a2+a3)) + RWs[5408+k];
            float gk = sg*0.5f*a*(1.f+erff(a*0.70710678f));
            const float4* w2 = (const float4*)(RWs + 2704 + k*52);
            #pragma unroll
            for (int t=0;t<13;t++){
                float4 w = w2[t];
                racc[4*t+0]=fmaf(gk,w.x,racc[4*t+0]); racc[4*t+1]=fmaf(gk,w.y,racc[4*t+1]);
                racc[4*t+2]=fmaf(gk,w.z,racc[4*t+2]); racc[4*t+3]=fmaf(gk,w.w,racc[4*t+3]);
            }
        }

        float4* o4 = (float4*)(out + (size_t)row*56);
        #pragma unroll
        for (int t=0;t<13;t++){
            float4 v;
            v.x = emb[4*t+0] + fmaf(sg, RWs[5460+4*t+0], racc[4*t+0]);
            v.y = emb[4*t+1] + fmaf(sg, RWs[5460+4*t+1], racc[4*t+1]);
            v.z = emb[4*t+2] + fmaf(sg, RWs[5460+4*t+2], racc[4*t+2]);
            v.w = emb[4*t+3] + fmaf(sg, RWs[5460+4*t+3], racc[4*t+3]);
            o4[t] = v;
        }
        o4[13] = make_float4(emb[52], emb[53], emb[54], emb[55]);
    }
}

// ============ K2: f64 rescue + fused refine ==================================
__global__ __launch_bounds__(RTPB) void e8_rescue(
    const float* __restrict__ g_obs,
    const float* __restrict__ pw1, const float* __restrict__ pb1,
    const float* __restrict__ pw2, const float* __restrict__ pb2,
    const float* __restrict__ lemb, const float* __restrict__ bcp,
    const float* __restrict__ rcpar, const float* __restrict__ bcx,
    const float* __restrict__ glogdecay,
    const float* __restrict__ rw1, const float* __restrict__ rb1,
    const float* __restrict__ rw2, const float* __restrict__ rb2,
    const float* __restrict__ rgate,
    const u32* __restrict__ cnt, const u32* __restrict__ list,
    const unsigned char* __restrict__ flags, int useCompact,
    float* __restrict__ out, int B)
{
    __shared__ float L[LDSZ];
    __shared__ float Ttab[RTPB*25];
    __shared__ __align__(16) float RWs[5512];
    const int tid = threadIdx.x;
    int row = -1;
    bool valid;
    if (useCompact){
        u32 c = *cnt;
        if ((u32)(blockIdx.x*RTPB) >= c) return;
        int gid = blockIdx.x*RTPB + tid;
        valid = (gid < (int)c);
        if (valid) row = (int)list[gid];
    } else {
        row = blockIdx.x*RTPB + tid;
        valid = (row < B) && (flags[row] != 0);
        if (!__syncthreads_or(valid ? 1 : 0)) return;
    }
    stageL(L, tid, RTPB, lemb, bcp, bcx);
    stageRW(RWs, tid, RTPB, rw1, rw2, rb1, rb2);
    __syncthreads();
    if (!valid) return;

    double ob[14];
    #pragma unroll
    for (int j=0;j<14;j++) ob[j] = (double)g_obs[(size_t)row*14+j];
    double qa[8];
    #pragma unroll
    for (int m=0;m<8;m++) qa[m] = (double)pb2[m];
    #pragma unroll 1
    for (int k=0;k<32;k++){
        double a = (double)pb1[k];
        #pragma unroll
        for (int j=0;j<14;j++) a += (double)pw1[k*14+j]*ob[j];
        double hk = 0.5*a*(1.0 + erf(a*0.70710678118654752440));
        #pragma unroll
        for (int m=0;m<8;m++) qa[m] += (double)pw2[m*32+k]*hk;
    }
    double n2 = 0.0;
    #pragma unroll
    for (int m=0;m<8;m++) n2 += qa[m]*qa[m];
    double nr = sqrt(n2); if (nr < 1e-12) nr = 1e-12;
    double q[8], residual[8];
    #pragma unroll
    for (int m=0;m<8;m++){ q[m] = qa[m]/nr*1.4142135623730951; residual[m]=q[m]; }

    double decay_d = exp((double)glogdecay[0]);
    double dpow = 1.0;
    int idxs[8] = {0,0,0,0,0,0,0,0};
    #pragma unroll
    for (int lvl=0; lvl<8; ++lvl){
        double rs = 0.5*dpow;
        double x[8];
        #pragma unroll
        for (int k=0;k<8;k++) x[k]=residual[k]*rs;
        idxs[lvl] = scan_fast_f64(x, 2.0/dpow, residual);
        dpow *= decay_d;
    }
    float qf[8];
    #pragma unroll
    for (int m=0;m<8;m++) qf[m]=(float)q[m];
    float sg = 1.f/(1.f+__expf(-rgate[0]));
    phaseB(L, Ttab + tid*25, qf, idxs[1],idxs[2],idxs[3],idxs[4],idxs[5],idxs[6],idxs[7],
           (float)decay_d, lemb, rcpar, RWs, sg, out + (size_t)row*56);
}

extern "C" void kernel_launch(void* const* d_in, const int* in_sizes, int n_in,
                              void* d_out, int out_size, void* d_ws, size_t ws_size,
                              hipStream_t stream)
{
    const float* obs  = (const float*)d_in[0];
    const float* pw1  = (const float*)d_in[1];
    const float* pb1  = (const float*)d_in[2];
    const float* pw2  = (const float*)d_in[3];
    const float* pb2  = (const float*)d_in[4];
    const float* lemb = (const float*)d_in[5];
    const float* bcp  = (const float*)d_in[6];
    const float* rcp  = (const float*)d_in[7];
    const float* bcx  = (const float*)d_in[8];
    const float* ld   = (const float*)d_in[9];
    const float* rw1  = (const float*)d_in[10];
    const float* rb1  = (const float*)d_in[11];
    const float* rw2  = (const float*)d_in[12];
    const float* rb2  = (const float*)d_in[13];
    const float* rg   = (const float*)d_in[14];

    int B = in_sizes[0] / 14;
    int grid  = (B + TPB - 1) / TPB;
    int rgrid = (B + RTPB - 1) / RTPB;

    bool compact = ws_size >= (size_t)256 + (size_t)B*4;
    u32* cnt  = (u32*)d_ws;
    u32* list = (u32*)d_ws + 64;
    unsigned char* flags = (unsigned char*)d_ws + 256;

    hipMemsetAsync(d_ws, 0, 8, stream);

    e8_main<<<grid, TPB, 0, stream>>>(obs, pw1, pb1, pw2, pb2, lemb, bcp, rcp, bcx, ld,
                                      rw1, rb1, rw2, rb2, rg,
                                      cnt, list, flags, compact?1:0, (float*)d_out, B);
    e8_rescue<<<rgrid, RTPB, 0, stream>>>(obs, pw1, pb1, pw2, pb2, lemb, bcp, rcp, bcx, ld,
                                          rw1, rb1, rw2, rb2, rg,
                                          cnt, list, flags, compact?1:0, (float*)d_out, B);
}

// Round 8
// 434.964 us; speedup vs baseline: 1.1445x; 1.1445x over previous
//
#include <hip/hip_runtime.h>
#include <hip/hip_bf16.h>
#include <math.h>

#define TPB  256     // phaseA / phaseB / refine
#define RTPB 128     // rescue
#define EPS_GAP 1e-4f
#define LTAB 13440   // 240*56 fused [lemb0|bcp] table (floats) -- rescue only
#define LDSZ 13680   // + 240 bcx                               -- rescue only

typedef unsigned int u32;
typedef unsigned long long u64;
typedef __attribute__((ext_vector_type(8))) short bf16x8;
typedef __attribute__((ext_vector_type(4))) float f32x4;

// ============ analytic fp32 scan: O(8) per level =============================
__device__ __forceinline__ int scan_fast(const float* x, float scale,
                                         float* residual, bool protect, bool& flag){
    float aa[8]; int neg=0; float S=0.f;
    #pragma unroll
    for (int k=0;k<8;k++){
        float v=x[k]; float av=fabsf(v);
        aa[k]=av; S+=av; neg |= (v<0.f)?(1<<k):0;
    }
    float t1=-1e30f,t2=-1e30f,t3=-1e30f; int p1=0,p2=0;
    #pragma unroll
    for (int k=0;k<8;k++){
        float v=aa[k];
        bool g1=v>t1, g2=v>t2, g3=v>t3;
        t3 = g2 ? t2 : (g3 ? v : t3);
        t2 = g1 ? t1 : (g2 ? v : t2);
        p2 = g1 ? p1 : (g2 ? k : p2);
        t1 = g1 ? v : t1;
        p1 = g1 ? k : p1;
    }
    float n1=1e30f,n2v=1e30f; int m1=0;
    #pragma unroll
    for (int k=0;k<8;k++){
        float v=aa[k];
        bool l1=v<n1, l2=v<n2v;
        n2v = l1 ? n1 : (l2 ? v : n2v);
        n1  = l1 ? v : n1;
        m1  = l1 ? k : m1;
    }
    int bi = min(p1,p2), bj = max(p1,p2);
    float pv = 2.f*(t1+t2), pr = 2.f*(t1+t3);
    int par = __builtin_popcount((unsigned)neg)&1;
    float hv, hr; int hb;
    if (par==0){ hv=S;          hb=neg;           hr=S-2.f*(n1+n2v); }
    else       { hv=S-2.f*n1;   hb=neg^(1<<m1);   hr=S-2.f*n2v; }
    bool pair = (pv >= hv);
    float best = pair? pv: hv, alt = pair? hv: pv;
    float second = fmaxf(alt, fmaxf(pr,hr));
    if (protect) flag = flag || ((best-second) < EPS_GAP);
    int s = (((neg>>bi)&1)<<1) | ((neg>>bj)&1);
    int pidx = 4*(7*bi - ((bi*(bi-1))>>1) + (bj-bi-1)) + s;
    int hidx = 112 + (hb>>1);
    float sI = ((neg>>bi)&1)? scale : -scale;
    float sJ = ((neg>>bj)&1)? scale : -scale;
    #pragma unroll
    for (int k=0;k<8;k++){
        float cp = ((k==bi)? sI:0.f) + ((k==bj)? sJ:0.f);
        float ch = ((hb>>k)&1)? 0.5f*scale : -0.5f*scale;
        residual[k] += (pair? cp : ch);
    }
    return pair? pidx : hidx;
}

// ============ analytic f64 scan (rescue) ======================================
__device__ __forceinline__ int scan_fast_f64(const double* x, double scale,
                                             double* residual){
    double aa[8]; int neg=0; double S=0.0;
    #pragma unroll
    for (int k=0;k<8;k++){
        double v=x[k]; double av=fabs(v);
        aa[k]=av; S+=av; neg |= (v<0.0)?(1<<k):0;
    }
    double t1=-1e300,t2=-1e300; int p1=0,p2=0;
    #pragma unroll
    for (int k=0;k<8;k++){
        double v=aa[k];
        bool g1=v>t1, g2=v>t2;
        t2 = g1 ? t1 : (g2 ? v : t2);
        p2 = g1 ? p1 : (g2 ? k : p2);
        t1 = g1 ? v : t1;
        p1 = g1 ? k : p1;
    }
    double n1=1e300; int m1=0;
    #pragma unroll
    for (int k=0;k<8;k++){
        double v=aa[k];
        bool l1=v<n1;
        n1 = l1 ? v : n1;
        m1 = l1 ? k : m1;
    }
    int bi = min(p1,p2), bj = max(p1,p2);
    double pv = 2.0*(t1+t2);
    int par = __builtin_popcount((unsigned)neg)&1;
    double hv; int hb;
    if (par==0){ hv=S;          hb=neg; }
    else       { hv=S-2.0*n1;   hb=neg^(1<<m1); }
    bool pair = (pv >= hv);
    int s = (((neg>>bi)&1)<<1) | ((neg>>bj)&1);
    int pidx = 4*(7*bi - ((bi*(bi-1))>>1) + (bj-bi-1)) + s;
    int hidx = 112 + (hb>>1);
    double sI = ((neg>>bi)&1)? scale : -scale;
    double sJ = ((neg>>bj)&1)? scale : -scale;
    #pragma unroll
    for (int k=0;k<8;k++){
        double cp = ((k==bi)? sI:0.0) + ((k==bj)? sJ:0.0);
        double ch = ((hb>>k)&1)? 0.5*scale : -0.5*scale;
        residual[k] += (pair? cp : ch);
    }
    return pair? pidx : hidx;
}

// ============ scalar phase B (RESCUE ONLY — pre-refine) =======================
__device__ __forceinline__ void phaseB(const float* __restrict__ L, float* T,
    const float* qf,
    int i1,int i2,int i3,int i4,int i5,int i6,int i7, float decay,
    const float* __restrict__ lemb, const float* __restrict__ rcpar,
    float* __restrict__ orow)
{
    const float IS2 = 0.70710678118654752f;
    const float HS2 = 0.35355339059327376f;
    const float LG2 = 0.69314718055994531f;
    float hi16[16];
    {
        float a01p=qf[0]+qf[1], a01m=qf[0]-qf[1];
        float a23p=qf[2]+qf[3], a23m=qf[2]-qf[3];
        float a45p=qf[4]+qf[5], a45m=qf[4]-qf[5];
        float a67p=qf[6]+qf[7], a67m=qf[6]-qf[7];
        float s01[4]={a01p,-a01m,a01m,-a01p};
        float s23[4]={a23p,-a23m,a23m,-a23p};
        float s45[4]={a45p,-a45m,a45m,-a45p};
        float s67[4]={a67p,-a67m,a67m,-a67p};
        #pragma unroll
        for (int p=0;p<16;p++){ T[8+p]=s01[p&3]+s23[(p>>2)&3]; hi16[p]=s45[p&3]+s67[(p>>2)&3]; }
        #pragma unroll
        for (int k=0;k<8;k++) T[k]=qf[k];
    }
    float emb[56], den=0.f;
    #pragma unroll
    for (int k=0;k<56;k++) emb[k]=0.f;

    auto proc = [&](float sims, int j){
        float e = __expf(sims - L[LTAB + j]*LG2);
        den += e;
        const float4* Lr = (const float4*)(L + j*56);
        #pragma unroll
        for (int t=0;t<14;t++){
            float4 v = Lr[t];
            emb[4*t+0]=fmaf(e,v.x,emb[4*t+0]); emb[4*t+1]=fmaf(e,v.y,emb[4*t+1]);
            emb[4*t+2]=fmaf(e,v.z,emb[4*t+2]); emb[4*t+3]=fmaf(e,v.w,emb[4*t+3]);
        }
    };
    #pragma unroll
    for (int h=0;h<16;h++){
        float hv = hi16[h];
        int ph = __builtin_popcount(h)&1;
        #pragma unroll 1
        for (int m=0;m<8;m++){
            int lo = (m<<1) | ((__builtin_popcount(m)&1)^ph);
            proc((T[8+lo]+hv)*HS2, 112 + (h<<3) + m);
        }
    }
    {
        int ii=0, jn=1;
        #pragma unroll 1
        for (int pc=0;pc<28;++pc){
            float a=T[ii], b=T[jn];
            float p=a+b, mm=a-b;
            proc( p*IS2, 4*pc+0);
            proc( mm*IS2,4*pc+1);
            proc(-mm*IS2,4*pc+2);
            proc(-p*IS2, 4*pc+3);
            if (++jn==8){ ++ii; jn=ii+1; }
        }
    }
    float rden = 1.f/den;
    #pragma unroll
    for (int k=0;k<56;k++) emb[k] *= rden;

    {
        float dp = decay;
        #define DO_G(LVL, IV) { \
            float ild = 1.0f/dp; \
            const float4* ep4 = (const float4*)(lemb + ((size_t)(LVL)*240 + (size_t)(IV))*52); \
            _Pragma("unroll") for (int t4=0;t4<13;t4++){ float4 v=ep4[t4]; \
                emb[4*t4+0]=fmaf(ild,v.x,emb[4*t4+0]); emb[4*t4+1]=fmaf(ild,v.y,emb[4*t4+1]); \
                emb[4*t4+2]=fmaf(ild,v.z,emb[4*t4+2]); emb[4*t4+3]=fmaf(ild,v.w,emb[4*t4+3]); } \
            float4 cv = *(const float4*)(rcpar + ((size_t)((LVL)-1)*240 + (size_t)(IV))*4); \
            emb[52]=fmaf(ild,cv.x,emb[52]); emb[53]=fmaf(ild,cv.y,emb[53]); \
            emb[54]=fmaf(ild,cv.z,emb[54]); emb[55]=fmaf(ild,cv.w,emb[55]); \
            dp *= decay; }
        DO_G(1,i1) DO_G(2,i2) DO_G(3,i3) DO_G(4,i4) DO_G(5,i5) DO_G(6,i6) DO_G(7,i7)
        #undef DO_G
    }
    float4* o4 = (float4*)orow;
    #pragma unroll
    for (int t=0;t<14;t++)
        o4[t] = make_float4(emb[4*t], emb[4*t+1], emb[4*t+2], emb[4*t+3]);
}

__device__ __forceinline__ void stageL(float* L, int tid, int tpb,
    const float* __restrict__ lemb, const float* __restrict__ bcp,
    const float* __restrict__ bcx)
{
    for (int t = tid; t < LTAB; t += tpb){
        int j = t/56, c = t - j*56;
        L[t] = (c < 52) ? lemb[j*52 + c] : bcp[j*4 + (c-52)];
    }
    for (int t = tid; t < 240; t += tpb) L[LTAB + t] = bcx[t];
}

// ============ helpers for MFMA phase B =======================================
__device__ __forceinline__ unsigned short f2bf(float x){
    union{float f; u32 u;} c; c.f = x;
    u32 u = c.u + 0x7fffu + ((c.u>>16)&1u);
    return (unsigned short)(u>>16);
}
__device__ __forceinline__ u32 pk2(float a, float b){
    union { __hip_bfloat162 h; u32 u; } cv;
    cv.h = __float22bfloat162_rn(make_float2(a,b));
    return cv.u;
}

#define BT_PITCH 264
#define E_PITCH  260
#define SCR_PITCH 68

#define EP4(i,jn,J,W) { \
    float P=(qf[i]+qf[jn])*IS2, M=(qf[i]-qf[jn])*IS2; \
    float e0=__expf(fmaf(-LG2,bcxL[(J)+0],P)); \
    float e1=__expf(fmaf(-LG2,bcxL[(J)+1],M)); \
    float e2=__expf(fmaf(-LG2,bcxL[(J)+2],-M)); \
    float e3=__expf(fmaf(-LG2,bcxL[(J)+3],-P)); \
    den += ((e0+e1)+(e2+e3)); \
    ESH[((W)+0)*E_PITCH + tid]=pk2(e0,e1); \
    ESH[((W)+1)*E_PITCH + tid]=pk2(e2,e3); }

// lo16[p] == s01[p&3]+s23[p>>2], hi16[h] == s45[h&3]+s67[h>>2]; recomputing per
// use (compile-time indices) is bit-identical and saves 16 arch VGPRs.
#define LOV(Lx) (s01[(Lx)&3]+s23[(Lx)>>2])
#define EH8(h,J,W,L0,L1,L2,L3,L4,L5,L6,L7) { \
    float hv=s45[(h)&3]+s67[(h)>>2]; \
    float e0=__expf(fmaf(-LG2,bcxL[(J)+0],(LOV(L0)+hv)*HS2)); \
    float e1=__expf(fmaf(-LG2,bcxL[(J)+1],(LOV(L1)+hv)*HS2)); \
    float e2=__expf(fmaf(-LG2,bcxL[(J)+2],(LOV(L2)+hv)*HS2)); \
    float e3=__expf(fmaf(-LG2,bcxL[(J)+3],(LOV(L3)+hv)*HS2)); \
    float e4=__expf(fmaf(-LG2,bcxL[(J)+4],(LOV(L4)+hv)*HS2)); \
    float e5=__expf(fmaf(-LG2,bcxL[(J)+5],(LOV(L5)+hv)*HS2)); \
    float e6=__expf(fmaf(-LG2,bcxL[(J)+6],(LOV(L6)+hv)*HS2)); \
    float e7=__expf(fmaf(-LG2,bcxL[(J)+7],(LOV(L7)+hv)*HS2)); \
    den += (((e0+e1)+(e2+e3))+((e4+e5)+(e6+e7))); \
    ESH[((W)+0)*E_PITCH + tid]=pk2(e0,e1); \
    ESH[((W)+1)*E_PITCH + tid]=pk2(e2,e3); \
    ESH[((W)+2)*E_PITCH + tid]=pk2(e4,e5); \
    ESH[((W)+3)*E_PITCH + tid]=pk2(e6,e7); }

#define EFLUSH(c) { \
    union { u32 u[4]; bf16x8 v; } Af; \
    const unsigned short* bp = BtT + pp*BT_PITCH + qq*8 + (c)*32; \
    bf16x8 b0 = *(const bf16x8*)(const void*)(bp); \
    bf16x8 b1 = *(const bf16x8*)(const void*)(bp + 16*BT_PITCH); \
    bf16x8 b2 = *(const bf16x8*)(const void*)(bp + 32*BT_PITCH); \
    bf16x8 b3 = *(const bf16x8*)(const void*)(bp + 48*BT_PITCH); \
    _Pragma("unroll") for (int s4=0;s4<4;s4++){ \
        const u32* ep = ESH + (4*qq)*E_PITCH + wbase + 16*s4 + pp; \
        Af.u[0]=ep[0]; Af.u[1]=ep[E_PITCH]; Af.u[2]=ep[2*E_PITCH]; Af.u[3]=ep[3*E_PITCH]; \
        acc[s4][0]=__builtin_amdgcn_mfma_f32_16x16x32_bf16(Af.v,b0,acc[s4][0],0,0,0); \
        acc[s4][1]=__builtin_amdgcn_mfma_f32_16x16x32_bf16(Af.v,b1,acc[s4][1],0,0,0); \
        acc[s4][2]=__builtin_amdgcn_mfma_f32_16x16x32_bf16(Af.v,b2,acc[s4][2],0,0,0); \
        acc[s4][3]=__builtin_amdgcn_mfma_f32_16x16x32_bf16(Af.v,b3,acc[s4][3],0,0,0); \
    } }

// ============ K_A: fp32 MLP + analytic scan; writes q + packed idxs into out ==
__global__ __launch_bounds__(TPB) void e8_phaseA(
    const float* __restrict__ g_obs,
    const float* __restrict__ pw1, const float* __restrict__ pb1,
    const float* __restrict__ pw2, const float* __restrict__ pb2,
    const float* __restrict__ glogdecay,
    u32* __restrict__ cnt, u32* __restrict__ list,
    unsigned char* __restrict__ flags, int useCompact,
    float* __restrict__ out, int B)
{
    __shared__ float obsF[TPB*17];     // 17.4 KB coalesced obs staging
    const int tid = threadIdx.x;
    const int row = blockIdx.x*TPB + tid;
    const bool active = row < B;
    const int lane = tid & 63;

    {
        const size_t base = (size_t)blockIdx.x*TPB*14;
        const size_t lim  = (size_t)B*14;
        for (int t = tid; t < TPB*14; t += TPB){
            size_t g = base + (size_t)t;
            float v = (g < lim) ? g_obs[g] : 0.f;
            int r = t/14, c = t - r*14;
            obsF[r*17 + c] = v;
        }
    }
    __syncthreads();

    float qf[8];
    int idxs[8] = {0,0,0,0,0,0,0,0};
    bool flag = false;
    {
        float ob[14];
        #pragma unroll
        for (int j=0;j<14;j++) ob[j]=obsF[tid*17+j];
        float qa[8];
        #pragma unroll
        for (int m=0;m<8;m++) qa[m]=pb2[m];
        #pragma unroll 1
        for (int k=0;k<32;k++){
            float a = pb1[k];
            #pragma unroll
            for (int j=0;j<14;j++) a = fmaf(pw1[k*14+j], ob[j], a);
            float h = 0.5f*a*(1.f+erff(a*0.70710678f));
            #pragma unroll
            for (int m=0;m<8;m++) qa[m] = fmaf(pw2[m*32+k], h, qa[m]);
        }
        float n2=0.f;
        #pragma unroll
        for (int m=0;m<8;m++) n2 = fmaf(qa[m],qa[m],n2);
        float nr = fmaxf(sqrtf(n2), 1e-12f);
        float sc = 1.41421356237309505f/nr;
        float residual[8];
        #pragma unroll
        for (int m=0;m<8;m++){ qf[m]=qa[m]*sc; residual[m]=qf[m]; }

        float decay = expf(glogdecay[0]);
        float dpow = 1.f;
        #pragma unroll
        for (int lvl=0; lvl<8; ++lvl){
            float rs = 0.5f*dpow;
            float x[8];
            #pragma unroll
            for (int k=0;k<8;k++) x[k]=residual[k]*rs;
            idxs[lvl] = scan_fast(x, 2.f/dpow, residual, (lvl<3), flag);
            dpow *= decay;
        }
    }
    flag = flag && active;

    if (useCompact){
        u64 mask = __ballot(flag);
        if (mask){
            int leader = __builtin_ctzll(mask);
            u32 base = 0;
            if (lane == leader) base = atomicAdd(cnt, (u32)__builtin_popcountll(mask));
            base = __shfl(base, leader, 64);
            if (flag){
                u32 pos = (u32)__builtin_popcountll(mask & ((1ull<<lane)-1ull));
                list[base+pos] = (u32)row;
            }
        }
    } else if (active){
        flags[row] = flag ? 1 : 0;
    }

    if (active){
        float* orow = out + (size_t)row*56;
        *(float4*)(orow+0) = make_float4(qf[0],qf[1],qf[2],qf[3]);
        *(float4*)(orow+4) = make_float4(qf[4],qf[5],qf[6],qf[7]);
        u32 iw0 = (u32)idxs[1] | ((u32)idxs[2]<<8) | ((u32)idxs[3]<<16) | ((u32)idxs[4]<<24);
        u32 iw1 = (u32)idxs[5] | ((u32)idxs[6]<<8) | ((u32)idxs[7]<<16);
        union{ u32 u[2]; float2 f; } iv; iv.u[0]=iw0; iv.u[1]=iw1;
        *(float2*)(orow+8) = iv.f;
    }
}

// ============ K_B: MFMA softmax-GEMM + hard gathers (reads q/idxs from out) ===
// EXPERIMENT: __launch_bounds__(TPB, 2) on the LEAN kernel. Model from R2/R4:
// hint => arch cap = budget - rounded AGPR block = 128. The lean GEMM live set
// (~80-110 after the s-table diet) may fit 128 => 2 waves/SIMD (vs 1 now).
// Tripwire: WRITE_SIZE > 90 MB or dur >= 150us => spilled => revert to R6.
__global__ __launch_bounds__(TPB, 2) void e8_phaseB(
    const float* __restrict__ lemb, const float* __restrict__ bcp,
    const float* __restrict__ rcpar, const float* __restrict__ bcx,
    const float* __restrict__ glogdecay,
    float* __restrict__ out, int B)
{
    const float IS2 = 0.70710678118654752f;
    const float HS2 = 0.35355339059327376f;
    const float LG2 = 0.69314718055994531f;

    __shared__ __align__(16) unsigned short BtT[64*BT_PITCH]; // 33792 B bf16 L^T
    __shared__ __align__(16) char UN[17408];                  // E / scratch union
    __shared__ float bcxL[240];
    u32*   ESH  = (u32*)UN;
    float* scrF = (float*)UN;

    const int tid  = threadIdx.x;
    const int row  = blockIdx.x*TPB + tid;
    const bool active = row < B;
    const int lane = tid & 63;
    const int qq = lane >> 4, pp = lane & 15;
    const int wbase = tid & 192;       // wave index * 64

    // ---- staging: Bt (coalesced linear reads + LDS transpose writes), bcx ----
    for (int t = tid; t < 2048; t += TPB)          // cols 56..63, all k
        BtT[(56 + (t>>8))*BT_PITCH + (t&255)] = 0;
    for (int t = tid; t < 1024; t += TPB)          // all cols, k 240..255
        BtT[(t>>4)*BT_PITCH + 240 + (t&15)] = 0;
    for (int t = tid; t < 12480; t += TPB){        // lemb0: linear
        int k = t/52, c = t - k*52;
        BtT[c*BT_PITCH + k] = f2bf(lemb[t]);
    }
    for (int t = tid; t < 960; t += TPB){          // bcp: linear
        int k = t>>2, c = 52 + (t&3);
        BtT[c*BT_PITCH + k] = f2bf(bcp[t]);
    }
    for (int t = tid; t < 240; t += TPB) bcxL[t] = bcx[t];

    // ---- per-row inputs from phase A (issued before barrier) ----
    float qf[8];
    u32 iw0=0, iw1=0;
    if (active){
        const float* orow = out + (size_t)row*56;
        float4 q0 = *(const float4*)(orow+0);
        float4 q1 = *(const float4*)(orow+4);
        qf[0]=q0.x; qf[1]=q0.y; qf[2]=q0.z; qf[3]=q0.w;
        qf[4]=q1.x; qf[5]=q1.y; qf[6]=q1.z; qf[7]=q1.w;
        union{ float2 f; u32 u[2]; } iv;
        iv.f = *(const float2*)(orow+8);
        iw0 = iv.u[0]; iw1 = iv.u[1];
    } else {
        #pragma unroll
        for (int m=0;m<8;m++) qf[m]=0.f;
    }
    float decay = expf(glogdecay[0]);
    __syncthreads();

    // ---- Hadamard half-tables (16 regs; lo/hi recomputed per use) ----
    float s01[4], s23[4], s45[4], s67[4];
    {
        float a01p=qf[0]+qf[1], a01m=qf[0]-qf[1];
        float a23p=qf[2]+qf[3], a23m=qf[2]-qf[3];
        float a45p=qf[4]+qf[5], a45m=qf[4]-qf[5];
        float a67p=qf[6]+qf[7], a67m=qf[6]-qf[7];
        s01[0]=a01p; s01[1]=-a01m; s01[2]=a01m; s01[3]=-a01p;
        s23[0]=a23p; s23[1]=-a23m; s23[2]=a23m; s23[3]=-a23p;
        s45[0]=a45p; s45[1]=-a45m; s45[2]=a45m; s45[3]=-a45p;
        s67[0]=a67p; s67[1]=-a67m; s67[2]=a67m; s67[3]=-a67p;
    }

    // ---- chunked softmax-GEMM: E[64,240] x L[240,64] on MFMA ----
    f32x4 acc[4][4];
    #pragma unroll
    for (int s=0;s<4;s++)
        #pragma unroll
        for (int n=0;n<4;n++)
            acc[s][n] = f32x4{0.f,0.f,0.f,0.f};
    float den = 0.f;

    EP4(0,1,  0, 0) EP4(0,2,  4, 2) EP4(0,3,  8, 4) EP4(0,4, 12, 6)
    EP4(0,5, 16, 8) EP4(0,6, 20,10) EP4(0,7, 24,12) EP4(1,2, 28,14)
    EFLUSH(0)
    EP4(1,3, 32, 0) EP4(1,4, 36, 2) EP4(1,5, 40, 4) EP4(1,6, 44, 6)
    EP4(1,7, 48, 8) EP4(2,3, 52,10) EP4(2,4, 56,12) EP4(2,5, 60,14)
    EFLUSH(1)
    EP4(2,6, 64, 0) EP4(2,7, 68, 2) EP4(3,4, 72, 4) EP4(3,5, 76, 6)
    EP4(3,6, 80, 8) EP4(3,7, 84,10) EP4(4,5, 88,12) EP4(4,6, 92,14)
    EFLUSH(2)
    EP4(4,7, 96, 0) EP4(5,6,100, 2) EP4(5,7,104, 4) EP4(6,7,108, 6)
    EH8(0,112, 8, 0,3,5,6,9,10,12,15)
    EH8(1,120,12, 1,2,4,7,8,11,13,14)
    EFLUSH(3)
    EH8(2,128, 0, 1,2,4,7,8,11,13,14)
    EH8(3,136, 4, 0,3,5,6,9,10,12,15)
    EH8(4,144, 8, 1,2,4,7,8,11,13,14)
    EH8(5,152,12, 0,3,5,6,9,10,12,15)
    EFLUSH(4)
    EH8(6,160, 0, 0,3,5,6,9,10,12,15)
    EH8(7,168, 4, 1,2,4,7,8,11,13,14)
    EH8(8,176, 8, 1,2,4,7,8,11,13,14)
    EH8(9,184,12, 0,3,5,6,9,10,12,15)
    EFLUSH(5)
    EH8(10,192, 0, 0,3,5,6,9,10,12,15)
    EH8(11,200, 4, 1,2,4,7,8,11,13,14)
    EH8(12,208, 8, 0,3,5,6,9,10,12,15)
    EH8(13,216,12, 1,2,4,7,8,11,13,14)
    EFLUSH(6)
    EH8(14,224, 0, 1,2,4,7,8,11,13,14)
    EH8(15,232, 4, 0,3,5,6,9,10,12,15)
    #pragma unroll
    for (int w2=8; w2<16; w2++) ESH[w2*E_PITCH + tid]=0u;
    EFLUSH(7)

    __syncthreads();   // all waves' E reads done -> region reusable as scratch

    // ---- epilogue: transpose D back via per-wave scratch ----
    float emb[56];
    float* scr = scrF + (tid>>6)*(16*SCR_PITCH);
    #pragma unroll
    for (int s=0;s<4;s++){
        #pragma unroll
        for (int n=0;n<4;n++){
            #pragma unroll
            for (int r=0;r<4;r++)
                scr[(4*qq+r)*SCR_PITCH + 16*n + pp] = acc[s][n][r];
        }
        if ((lane>>4) == s){
            const float4* rp = (const float4*)(scr + pp*SCR_PITCH);
            #pragma unroll
            for (int t=0;t<14;t++){
                float4 v = rp[t];
                emb[4*t]=v.x; emb[4*t+1]=v.y; emb[4*t+2]=v.z; emb[4*t+3]=v.w;
            }
        }
    }

    if (active){
        float rden = 1.f/den;
        #pragma unroll
        for (int k=0;k<56;k++) emb[k] *= rden;

        int i1 = iw0 & 255, i2 = (iw0>>8)&255, i3 = (iw0>>16)&255, i4 = (iw0>>24)&255;
        int i5 = iw1 & 255, i6 = (iw1>>8)&255, i7 = (iw1>>16)&255;

        float dp = decay;
        #define DO_G2(LVL, IV) { \
            float ild = 1.0f/dp; \
            const float4* ep4 = (const float4*)(lemb + ((size_t)(LVL)*240 + (size_t)(IV))*52); \
            _Pragma("unroll") for (int t4=0;t4<13;t4++){ float4 v=ep4[t4]; \
                emb[4*t4+0]=fmaf(ild,v.x,emb[4*t4+0]); emb[4*t4+1]=fmaf(ild,v.y,emb[4*t4+1]); \
                emb[4*t4+2]=fmaf(ild,v.z,emb[4*t4+2]); emb[4*t4+3]=fmaf(ild,v.w,emb[4*t4+3]); } \
            float4 cv = *(const float4*)(rcpar + ((size_t)((LVL)-1)*240 + (size_t)(IV))*4); \
            emb[52]=fmaf(ild,cv.x,emb[52]); emb[53]=fmaf(ild,cv.y,emb[53]); \
            emb[54]=fmaf(ild,cv.z,emb[54]); emb[55]=fmaf(ild,cv.w,emb[55]); \
            dp *= decay; }
        DO_G2(1,i1) DO_G2(2,i2) DO_G2(3,i3) DO_G2(4,i4)
        DO_G2(5,i5) DO_G2(6,i6) DO_G2(7,i7)
        #undef DO_G2

        float4* o4 = (float4*)(out + (size_t)row*56);
        #pragma unroll
        for (int t=0;t<14;t++)
            o4[t] = make_float4(emb[4*t], emb[4*t+1], emb[4*t+2], emb[4*t+3]);
    }
}

// ============ K2: f64 rescue (pre-refine) ====================================
__global__ __launch_bounds__(RTPB) void e8_rescue(
    const float* __restrict__ g_obs,
    const float* __restrict__ pw1, const float* __restrict__ pb1,
    const float* __restrict__ pw2, const float* __restrict__ pb2,
    const float* __restrict__ lemb, const float* __restrict__ bcp,
    const float* __restrict__ rcpar, const float* __restrict__ bcx,
    const float* __restrict__ glogdecay,
    const u32* __restrict__ cnt, const u32* __restrict__ list,
    const unsigned char* __restrict__ flags, int useCompact,
    float* __restrict__ out, int B)
{
    __shared__ float L[LDSZ];
    __shared__ float Ttab[RTPB*25];
    const int tid = threadIdx.x;
    int row = -1;
    bool valid;
    if (useCompact){
        u32 c = *cnt;
        if ((u32)(blockIdx.x*RTPB) >= c) return;
        int gid = blockIdx.x*RTPB + tid;
        valid = (gid < (int)c);
        if (valid) row = (int)list[gid];
    } else {
        row = blockIdx.x*RTPB + tid;
        valid = (row < B) && (flags[row] != 0);
        if (!__syncthreads_or(valid ? 1 : 0)) return;
    }
    stageL(L, tid, RTPB, lemb, bcp, bcx);
    __syncthreads();
    if (!valid) return;

    double ob[14];
    #pragma unroll
    for (int j=0;j<14;j++) ob[j] = (double)g_obs[(size_t)row*14+j];
    double qa[8];
    #pragma unroll
    for (int m=0;m<8;m++) qa[m] = (double)pb2[m];
    #pragma unroll 1
    for (int k=0;k<32;k++){
        double a = (double)pb1[k];
        #pragma unroll
        for (int j=0;j<14;j++) a += (double)pw1[k*14+j]*ob[j];
        double hk = 0.5*a*(1.0 + erf(a*0.70710678118654752440));
        #pragma unroll
        for (int m=0;m<8;m++) qa[m] += (double)pw2[m*32+k]*hk;
    }
    double n2 = 0.0;
    #pragma unroll
    for (int m=0;m<8;m++) n2 += qa[m]*qa[m];
    double nr = sqrt(n2); if (nr < 1e-12) nr = 1e-12;
    double q[8], residual[8];
    #pragma unroll
    for (int m=0;m<8;m++){ q[m] = qa[m]/nr*1.4142135623730951; residual[m]=q[m]; }

    double decay_d = exp((double)glogdecay[0]);
    double dpow = 1.0;
    int idxs[8] = {0,0,0,0,0,0,0,0};
    #pragma unroll
    for (int lvl=0; lvl<8; ++lvl){
        double rs = 0.5*dpow;
        double x[8];
        #pragma unroll
        for (int k=0;k<8;k++) x[k]=residual[k]*rs;
        idxs[lvl] = scan_fast_f64(x, 2.0/dpow, residual);
        dpow *= decay_d;
    }
    float qf[8];
    #pragma unroll
    for (int m=0;m<8;m++) qf[m]=(float)q[m];
    phaseB(L, Ttab + tid*25, qf, idxs[1],idxs[2],idxs[3],idxs[4],idxs[5],idxs[6],idxs[7],
           (float)decay_d, lemb, rcpar, out + (size_t)row*56);
}

// ============ K3: gated refinement MLP (standalone, proven) ==================
__global__ __launch_bounds__(TPB) void e8_refine(
    const float* __restrict__ rw1, const float* __restrict__ rb1,
    const float* __restrict__ rw2, const float* __restrict__ rb2,
    const float* __restrict__ rgate,
    float* __restrict__ out, int B)
{
    __shared__ float W1[2704];
    __shared__ float W2T[2704];
    __shared__ float Bv[104];
    const int tid = threadIdx.x;
    for (int t = tid; t < 2704; t += TPB) W1[t] = rw1[t];
    for (int t = tid; t < 2704; t += TPB){
        int m = t/52, k = t - m*52;
        W2T[k*52 + m] = rw2[t];
    }
    for (int t = tid; t < 104; t += TPB) Bv[t] = (t < 52) ? rb1[t] : rb2[t-52];
    __syncthreads();

    const int row = blockIdx.x*TPB + tid;
    if (row >= B) return;
    float* orow = out + (size_t)row*56;
    float emb[52];
    {
        const float4* o4 = (const float4*)orow;
        #pragma unroll
        for (int t=0;t<13;t++){
            float4 v = o4[t];
            emb[4*t]=v.x; emb[4*t+1]=v.y; emb[4*t+2]=v.z; emb[4*t+3]=v.w;
        }
    }
    float sg = 1.f/(1.f+__expf(-rgate[0]));
    float acc[52];
    #pragma unroll
    for (int m=0;m<52;m++) acc[m]=0.f;
    #pragma unroll 1
    for (int k=0;k<52;k++){
        const float4* w1 = (const float4*)(W1 + k*52);
        float a0=0.f,a1=0.f,a2=0.f,a3=0.f;
        #pragma unroll
        for (int t=0;t<13;t++){
            float4 w = w1[t];
            a0=fmaf(w.x,emb[4*t+0],a0); a1=fmaf(w.y,emb[4*t+1],a1);
            a2=fmaf(w.z,emb[4*t+2],a2); a3=fmaf(w.w,emb[4*t+3],a3);
        }
        float a = ((a0+a1)+(a2+a3)) + Bv[k];
        float gk = sg*0.5f*a*(1.f+erff(a*0.70710678f));
        const float4* w2 = (const float4*)(W2T + k*52);
        #pragma unroll
        for (int t=0;t<13;t++){
            float4 w = w2[t];
            acc[4*t+0]=fmaf(gk,w.x,acc[4*t+0]); acc[4*t+1]=fmaf(gk,w.y,acc[4*t+1]);
            acc[4*t+2]=fmaf(gk,w.z,acc[4*t+2]); acc[4*t+3]=fmaf(gk,w.w,acc[4*t+3]);
        }
    }
    float4* o4 = (float4*)orow;
    #pragma unroll
    for (int t=0;t<13;t++){
        float4 v;
        v.x = emb[4*t+0] + fmaf(sg, Bv[52+4*t+0], acc[4*t+0]);
        v.y = emb[4*t+1] + fmaf(sg, Bv[52+4*t+1], acc[4*t+1]);
        v.z = emb[4*t+2] + fmaf(sg, Bv[52+4*t+2], acc[4*t+2]);
        v.w = emb[4*t+3] + fmaf(sg, Bv[52+4*t+3], acc[4*t+3]);
        o4[t] = v;
    }
}

extern "C" void kernel_launch(void* const* d_in, const int* in_sizes, int n_in,
                              void* d_out, int out_size, void* d_ws, size_t ws_size,
                              hipStream_t stream)
{
    const float* obs  = (const float*)d_in[0];
    const float* pw1  = (const float*)d_in[1];
    const float* pb1  = (const float*)d_in[2];
    const float* pw2  = (const float*)d_in[3];
    const float* pb2  = (const float*)d_in[4];
    const float* lemb = (const float*)d_in[5];
    const float* bcp  = (const float*)d_in[6];
    const float* rcp  = (const float*)d_in[7];
    const float* bcx  = (const float*)d_in[8];
    const float* ld   = (const float*)d_in[9];
    const float* rw1  = (const float*)d_in[10];
    const float* rb1  = (const float*)d_in[11];
    const float* rw2  = (const float*)d_in[12];
    const float* rb2  = (const float*)d_in[13];
    const float* rg   = (const float*)d_in[14];

    int B = in_sizes[0] / 14;
    int grid  = (B + TPB - 1) / TPB;
    int rgrid = (B + RTPB - 1) / RTPB;

    bool compact = ws_size >= (size_t)256 + (size_t)B*4;
    u32* cnt  = (u32*)d_ws;
    u32* list = (u32*)d_ws + 64;
    unsigned char* flags = (unsigned char*)d_ws + 256;

    hipMemsetAsync(d_ws, 0, 8, stream);

    e8_phaseA<<<grid, TPB, 0, stream>>>(obs, pw1, pb1, pw2, pb2, ld,
                                        cnt, list, flags, compact?1:0, (float*)d_out, B);
    e8_phaseB<<<grid, TPB, 0, stream>>>(lemb, bcp, rcp, bcx, ld, (float*)d_out, B);
    e8_rescue<<<rgrid, RTPB, 0, stream>>>(obs, pw1, pb1, pw2, pb2, lemb, bcp, rcp, bcx, ld,
                                          cnt, list, flags, compact?1:0, (float*)d_out, B);
    e8_refine<<<grid, TPB, 0, stream>>>(rw1, rb1, rw2, rb2, rg, (float*)d_out, B);
}

// Round 9
// 408.024 us; speedup vs baseline: 1.2200x; 1.0660x over previous
//
#include <hip/hip_runtime.h>
#include <hip/hip_bf16.h>
#include <math.h>

#define TPB  256     // phaseA / phaseB / refine
#define RTPB 128     // rescue
#define EPS_GAP 1e-4f
#define LTAB 13440   // 240*56 fused [lemb0|bcp] table (floats) -- rescue only
#define LDSZ 13680   // + 240 bcx                               -- rescue only

typedef unsigned int u32;
typedef unsigned long long u64;
typedef __attribute__((ext_vector_type(8))) short bf16x8;
typedef __attribute__((ext_vector_type(4))) float f32x4;

// ============ analytic fp32 scan: O(8) per level =============================
__device__ __forceinline__ int scan_fast(const float* x, float scale,
                                         float* residual, bool protect, bool& flag){
    float aa[8]; int neg=0; float S=0.f;
    #pragma unroll
    for (int k=0;k<8;k++){
        float v=x[k]; float av=fabsf(v);
        aa[k]=av; S+=av; neg |= (v<0.f)?(1<<k):0;
    }
    float t1=-1e30f,t2=-1e30f,t3=-1e30f; int p1=0,p2=0;
    #pragma unroll
    for (int k=0;k<8;k++){
        float v=aa[k];
        bool g1=v>t1, g2=v>t2, g3=v>t3;
        t3 = g2 ? t2 : (g3 ? v : t3);
        t2 = g1 ? t1 : (g2 ? v : t2);
        p2 = g1 ? p1 : (g2 ? k : p2);
        t1 = g1 ? v : t1;
        p1 = g1 ? k : p1;
    }
    float n1=1e30f,n2v=1e30f; int m1=0;
    #pragma unroll
    for (int k=0;k<8;k++){
        float v=aa[k];
        bool l1=v<n1, l2=v<n2v;
        n2v = l1 ? n1 : (l2 ? v : n2v);
        n1  = l1 ? v : n1;
        m1  = l1 ? k : m1;
    }
    int bi = min(p1,p2), bj = max(p1,p2);
    float pv = 2.f*(t1+t2), pr = 2.f*(t1+t3);
    int par = __builtin_popcount((unsigned)neg)&1;
    float hv, hr; int hb;
    if (par==0){ hv=S;          hb=neg;           hr=S-2.f*(n1+n2v); }
    else       { hv=S-2.f*n1;   hb=neg^(1<<m1);   hr=S-2.f*n2v; }
    bool pair = (pv >= hv);
    float best = pair? pv: hv, alt = pair? hv: pv;
    float second = fmaxf(alt, fmaxf(pr,hr));
    if (protect) flag = flag || ((best-second) < EPS_GAP);
    int s = (((neg>>bi)&1)<<1) | ((neg>>bj)&1);
    int pidx = 4*(7*bi - ((bi*(bi-1))>>1) + (bj-bi-1)) + s;
    int hidx = 112 + (hb>>1);
    float sI = ((neg>>bi)&1)? scale : -scale;
    float sJ = ((neg>>bj)&1)? scale : -scale;
    #pragma unroll
    for (int k=0;k<8;k++){
        float cp = ((k==bi)? sI:0.f) + ((k==bj)? sJ:0.f);
        float ch = ((hb>>k)&1)? 0.5f*scale : -0.5f*scale;
        residual[k] += (pair? cp : ch);
    }
    return pair? pidx : hidx;
}

// ============ analytic f64 scan (rescue) ======================================
__device__ __forceinline__ int scan_fast_f64(const double* x, double scale,
                                             double* residual){
    double aa[8]; int neg=0; double S=0.0;
    #pragma unroll
    for (int k=0;k<8;k++){
        double v=x[k]; double av=fabs(v);
        aa[k]=av; S+=av; neg |= (v<0.0)?(1<<k):0;
    }
    double t1=-1e300,t2=-1e300; int p1=0,p2=0;
    #pragma unroll
    for (int k=0;k<8;k++){
        double v=aa[k];
        bool g1=v>t1, g2=v>t2;
        t2 = g1 ? t1 : (g2 ? v : t2);
        p2 = g1 ? p1 : (g2 ? k : p2);
        t1 = g1 ? v : t1;
        p1 = g1 ? k : p1;
    }
    double n1=1e300; int m1=0;
    #pragma unroll
    for (int k=0;k<8;k++){
        double v=aa[k];
        bool l1=v<n1;
        n1 = l1 ? v : n1;
        m1 = l1 ? k : m1;
    }
    int bi = min(p1,p2), bj = max(p1,p2);
    double pv = 2.0*(t1+t2);
    int par = __builtin_popcount((unsigned)neg)&1;
    double hv; int hb;
    if (par==0){ hv=S;          hb=neg; }
    else       { hv=S-2.0*n1;   hb=neg^(1<<m1); }
    bool pair = (pv >= hv);
    int s = (((neg>>bi)&1)<<1) | ((neg>>bj)&1);
    int pidx = 4*(7*bi - ((bi*(bi-1))>>1) + (bj-bi-1)) + s;
    int hidx = 112 + (hb>>1);
    double sI = ((neg>>bi)&1)? scale : -scale;
    double sJ = ((neg>>bj)&1)? scale : -scale;
    #pragma unroll
    for (int k=0;k<8;k++){
        double cp = ((k==bi)? sI:0.0) + ((k==bj)? sJ:0.0);
        double ch = ((hb>>k)&1)? 0.5*scale : -0.5*scale;
        residual[k] += (pair? cp : ch);
    }
    return pair? pidx : hidx;
}

// ============ scalar phase B (RESCUE ONLY — pre-refine) =======================
__device__ __forceinline__ void phaseB(const float* __restrict__ L, float* T,
    const float* qf,
    int i1,int i2,int i3,int i4,int i5,int i6,int i7, float decay,
    const float* __restrict__ lemb, const float* __restrict__ rcpar,
    float* __restrict__ orow)
{
    const float IS2 = 0.70710678118654752f;
    const float HS2 = 0.35355339059327376f;
    const float LG2 = 0.69314718055994531f;
    float hi16[16];
    {
        float a01p=qf[0]+qf[1], a01m=qf[0]-qf[1];
        float a23p=qf[2]+qf[3], a23m=qf[2]-qf[3];
        float a45p=qf[4]+qf[5], a45m=qf[4]-qf[5];
        float a67p=qf[6]+qf[7], a67m=qf[6]-qf[7];
        float s01[4]={a01p,-a01m,a01m,-a01p};
        float s23[4]={a23p,-a23m,a23m,-a23p};
        float s45[4]={a45p,-a45m,a45m,-a45p};
        float s67[4]={a67p,-a67m,a67m,-a67p};
        #pragma unroll
        for (int p=0;p<16;p++){ T[8+p]=s01[p&3]+s23[(p>>2)&3]; hi16[p]=s45[p&3]+s67[(p>>2)&3]; }
        #pragma unroll
        for (int k=0;k<8;k++) T[k]=qf[k];
    }
    float emb[56], den=0.f;
    #pragma unroll
    for (int k=0;k<56;k++) emb[k]=0.f;

    auto proc = [&](float sims, int j){
        float e = __expf(sims - L[LTAB + j]*LG2);
        den += e;
        const float4* Lr = (const float4*)(L + j*56);
        #pragma unroll
        for (int t=0;t<14;t++){
            float4 v = Lr[t];
            emb[4*t+0]=fmaf(e,v.x,emb[4*t+0]); emb[4*t+1]=fmaf(e,v.y,emb[4*t+1]);
            emb[4*t+2]=fmaf(e,v.z,emb[4*t+2]); emb[4*t+3]=fmaf(e,v.w,emb[4*t+3]);
        }
    };
    #pragma unroll
    for (int h=0;h<16;h++){
        float hv = hi16[h];
        int ph = __builtin_popcount(h)&1;
        #pragma unroll 1
        for (int m=0;m<8;m++){
            int lo = (m<<1) | ((__builtin_popcount(m)&1)^ph);
            proc((T[8+lo]+hv)*HS2, 112 + (h<<3) + m);
        }
    }
    {
        int ii=0, jn=1;
        #pragma unroll 1
        for (int pc=0;pc<28;++pc){
            float a=T[ii], b=T[jn];
            float p=a+b, mm=a-b;
            proc( p*IS2, 4*pc+0);
            proc( mm*IS2,4*pc+1);
            proc(-mm*IS2,4*pc+2);
            proc(-p*IS2, 4*pc+3);
            if (++jn==8){ ++ii; jn=ii+1; }
        }
    }
    float rden = 1.f/den;
    #pragma unroll
    for (int k=0;k<56;k++) emb[k] *= rden;

    {
        float dp = decay;
        #define DO_G(LVL, IV) { \
            float ild = 1.0f/dp; \
            const float4* ep4 = (const float4*)(lemb + ((size_t)(LVL)*240 + (size_t)(IV))*52); \
            _Pragma("unroll") for (int t4=0;t4<13;t4++){ float4 v=ep4[t4]; \
                emb[4*t4+0]=fmaf(ild,v.x,emb[4*t4+0]); emb[4*t4+1]=fmaf(ild,v.y,emb[4*t4+1]); \
                emb[4*t4+2]=fmaf(ild,v.z,emb[4*t4+2]); emb[4*t4+3]=fmaf(ild,v.w,emb[4*t4+3]); } \
            float4 cv = *(const float4*)(rcpar + ((size_t)((LVL)-1)*240 + (size_t)(IV))*4); \
            emb[52]=fmaf(ild,cv.x,emb[52]); emb[53]=fmaf(ild,cv.y,emb[53]); \
            emb[54]=fmaf(ild,cv.z,emb[54]); emb[55]=fmaf(ild,cv.w,emb[55]); \
            dp *= decay; }
        DO_G(1,i1) DO_G(2,i2) DO_G(3,i3) DO_G(4,i4) DO_G(5,i5) DO_G(6,i6) DO_G(7,i7)
        #undef DO_G
    }
    float4* o4 = (float4*)orow;
    #pragma unroll
    for (int t=0;t<14;t++)
        o4[t] = make_float4(emb[4*t], emb[4*t+1], emb[4*t+2], emb[4*t+3]);
}

__device__ __forceinline__ void stageL(float* L, int tid, int tpb,
    const float* __restrict__ lemb, const float* __restrict__ bcp,
    const float* __restrict__ bcx)
{
    for (int t = tid; t < LTAB; t += tpb){
        int j = t/56, c = t - j*56;
        L[t] = (c < 52) ? lemb[j*52 + c] : bcp[j*4 + (c-52)];
    }
    for (int t = tid; t < 240; t += tpb) L[LTAB + t] = bcx[t];
}

// ============ helpers for MFMA phase B =======================================
__device__ __forceinline__ unsigned short f2bf(float x){
    union{float f; u32 u;} c; c.f = x;
    u32 u = c.u + 0x7fffu + ((c.u>>16)&1u);
    return (unsigned short)(u>>16);
}
__device__ __forceinline__ u32 pk2(float a, float b){
    union { __hip_bfloat162 h; u32 u; } cv;
    cv.h = __float22bfloat162_rn(make_float2(a,b));
    return cv.u;
}

#define BT_PITCH 264
#define E_PITCH  260
#define SCR_PITCH 68

#define EP4(i,jn,J,W) { \
    float P=(qf[i]+qf[jn])*IS2, M=(qf[i]-qf[jn])*IS2; \
    float e0=__expf(fmaf(-LG2,bcxL[(J)+0],P)); \
    float e1=__expf(fmaf(-LG2,bcxL[(J)+1],M)); \
    float e2=__expf(fmaf(-LG2,bcxL[(J)+2],-M)); \
    float e3=__expf(fmaf(-LG2,bcxL[(J)+3],-P)); \
    den += ((e0+e1)+(e2+e3)); \
    ESH[((W)+0)*E_PITCH + tid]=pk2(e0,e1); \
    ESH[((W)+1)*E_PITCH + tid]=pk2(e2,e3); }

// lo16[p] == s01[p&3]+s23[p>>2], hi16[h] == s45[h&3]+s67[h>>2]; recomputing per
// use (compile-time indices) is bit-identical and saves 16 arch VGPRs.
#define LOV(Lx) (s01[(Lx)&3]+s23[(Lx)>>2])
#define EH8(h,J,W,L0,L1,L2,L3,L4,L5,L6,L7) { \
    float hv=s45[(h)&3]+s67[(h)>>2]; \
    float e0=__expf(fmaf(-LG2,bcxL[(J)+0],(LOV(L0)+hv)*HS2)); \
    float e1=__expf(fmaf(-LG2,bcxL[(J)+1],(LOV(L1)+hv)*HS2)); \
    float e2=__expf(fmaf(-LG2,bcxL[(J)+2],(LOV(L2)+hv)*HS2)); \
    float e3=__expf(fmaf(-LG2,bcxL[(J)+3],(LOV(L3)+hv)*HS2)); \
    float e4=__expf(fmaf(-LG2,bcxL[(J)+4],(LOV(L4)+hv)*HS2)); \
    float e5=__expf(fmaf(-LG2,bcxL[(J)+5],(LOV(L5)+hv)*HS2)); \
    float e6=__expf(fmaf(-LG2,bcxL[(J)+6],(LOV(L6)+hv)*HS2)); \
    float e7=__expf(fmaf(-LG2,bcxL[(J)+7],(LOV(L7)+hv)*HS2)); \
    den += (((e0+e1)+(e2+e3))+((e4+e5)+(e6+e7))); \
    ESH[((W)+0)*E_PITCH + tid]=pk2(e0,e1); \
    ESH[((W)+1)*E_PITCH + tid]=pk2(e2,e3); \
    ESH[((W)+2)*E_PITCH + tid]=pk2(e4,e5); \
    ESH[((W)+3)*E_PITCH + tid]=pk2(e6,e7); }

#define EFLUSH(c) { \
    union { u32 u[4]; bf16x8 v; } Af; \
    const unsigned short* bp = BtT + pp*BT_PITCH + qq*8 + (c)*32; \
    bf16x8 b0 = *(const bf16x8*)(const void*)(bp); \
    bf16x8 b1 = *(const bf16x8*)(const void*)(bp + 16*BT_PITCH); \
    bf16x8 b2 = *(const bf16x8*)(const void*)(bp + 32*BT_PITCH); \
    bf16x8 b3 = *(const bf16x8*)(const void*)(bp + 48*BT_PITCH); \
    _Pragma("unroll") for (int s4=0;s4<4;s4++){ \
        const u32* ep = ESH + (4*qq)*E_PITCH + wbase + 16*s4 + pp; \
        Af.u[0]=ep[0]; Af.u[1]=ep[E_PITCH]; Af.u[2]=ep[2*E_PITCH]; Af.u[3]=ep[3*E_PITCH]; \
        acc[s4][0]=__builtin_amdgcn_mfma_f32_16x16x32_bf16(Af.v,b0,acc[s4][0],0,0,0); \
        acc[s4][1]=__builtin_amdgcn_mfma_f32_16x16x32_bf16(Af.v,b1,acc[s4][1],0,0,0); \
        acc[s4][2]=__builtin_amdgcn_mfma_f32_16x16x32_bf16(Af.v,b2,acc[s4][2],0,0,0); \
        acc[s4][3]=__builtin_amdgcn_mfma_f32_16x16x32_bf16(Af.v,b3,acc[s4][3],0,0,0); \
    } }

// ============ K_A: fp32 MLP + analytic scan; writes q + packed idxs into out ==
__global__ __launch_bounds__(TPB) void e8_phaseA(
    const float* __restrict__ g_obs,
    const float* __restrict__ pw1, const float* __restrict__ pb1,
    const float* __restrict__ pw2, const float* __restrict__ pb2,
    const float* __restrict__ glogdecay,
    u32* __restrict__ cnt, u32* __restrict__ list,
    unsigned char* __restrict__ flags, int useCompact,
    float* __restrict__ out, int B)
{
    __shared__ float obsF[TPB*17];     // 17.4 KB coalesced obs staging
    const int tid = threadIdx.x;
    const int row = blockIdx.x*TPB + tid;
    const bool active = row < B;
    const int lane = tid & 63;

    {
        const size_t base = (size_t)blockIdx.x*TPB*14;
        const size_t lim  = (size_t)B*14;
        for (int t = tid; t < TPB*14; t += TPB){
            size_t g = base + (size_t)t;
            float v = (g < lim) ? g_obs[g] : 0.f;
            int r = t/14, c = t - r*14;
            obsF[r*17 + c] = v;
        }
    }
    __syncthreads();

    float qf[8];
    int idxs[8] = {0,0,0,0,0,0,0,0};
    bool flag = false;
    {
        float ob[14];
        #pragma unroll
        for (int j=0;j<14;j++) ob[j]=obsF[tid*17+j];
        float qa[8];
        #pragma unroll
        for (int m=0;m<8;m++) qa[m]=pb2[m];
        #pragma unroll 1
        for (int k=0;k<32;k++){
            float a = pb1[k];
            #pragma unroll
            for (int j=0;j<14;j++) a = fmaf(pw1[k*14+j], ob[j], a);
            float h = 0.5f*a*(1.f+erff(a*0.70710678f));
            #pragma unroll
            for (int m=0;m<8;m++) qa[m] = fmaf(pw2[m*32+k], h, qa[m]);
        }
        float n2=0.f;
        #pragma unroll
        for (int m=0;m<8;m++) n2 = fmaf(qa[m],qa[m],n2);
        float nr = fmaxf(sqrtf(n2), 1e-12f);
        float sc = 1.41421356237309505f/nr;
        float residual[8];
        #pragma unroll
        for (int m=0;m<8;m++){ qf[m]=qa[m]*sc; residual[m]=qf[m]; }

        float decay = expf(glogdecay[0]);
        float dpow = 1.f;
        #pragma unroll
        for (int lvl=0; lvl<8; ++lvl){
            float rs = 0.5f*dpow;
            float x[8];
            #pragma unroll
            for (int k=0;k<8;k++) x[k]=residual[k]*rs;
            idxs[lvl] = scan_fast(x, 2.f/dpow, residual, (lvl<3), flag);
            dpow *= decay;
        }
    }
    flag = flag && active;

    if (useCompact){
        u64 mask = __ballot(flag);
        if (mask){
            int leader = __builtin_ctzll(mask);
            u32 base = 0;
            if (lane == leader) base = atomicAdd(cnt, (u32)__builtin_popcountll(mask));
            base = __shfl(base, leader, 64);
            if (flag){
                u32 pos = (u32)__builtin_popcountll(mask & ((1ull<<lane)-1ull));
                list[base+pos] = (u32)row;
            }
        }
    } else if (active){
        flags[row] = flag ? 1 : 0;
    }

    if (active){
        float* orow = out + (size_t)row*56;
        *(float4*)(orow+0) = make_float4(qf[0],qf[1],qf[2],qf[3]);
        *(float4*)(orow+4) = make_float4(qf[4],qf[5],qf[6],qf[7]);
        u32 iw0 = (u32)idxs[1] | ((u32)idxs[2]<<8) | ((u32)idxs[3]<<16) | ((u32)idxs[4]<<24);
        u32 iw1 = (u32)idxs[5] | ((u32)idxs[6]<<8) | ((u32)idxs[7]<<16);
        union{ u32 u[2]; float2 f; } iv; iv.u[0]=iw0; iv.u[1]=iw1;
        *(float2*)(orow+8) = iv.f;
    }
}

// ============ K_B: MFMA softmax-GEMM + hard gathers (reads q/idxs from out) ===
// EXPERIMENT R9: cap UNIFIED regs at 256 via amdgpu_num_vgpr (NOT waves_per_eu,
// which splits the file 128/128 and spilled 121 MB in R8). Occupancy model
// (m69 + R5..R8): unified <=256 => 2 waves/SIMD. Allocator free to balance
// arch(~192)/AGPR(64). Tripwires: WRITE>90MB => spilled; VGPR>=208 & occ~11%
// => attribute ignored. Either => revert to R6 merged kernel.
__global__ __attribute__((amdgpu_num_vgpr(256))) __launch_bounds__(TPB) void e8_phaseB(
    const float* __restrict__ lemb, const float* __restrict__ bcp,
    const float* __restrict__ rcpar, const float* __restrict__ bcx,
    const float* __restrict__ glogdecay,
    float* __restrict__ out, int B)
{
    const float IS2 = 0.70710678118654752f;
    const float HS2 = 0.35355339059327376f;
    const float LG2 = 0.69314718055994531f;

    __shared__ __align__(16) unsigned short BtT[64*BT_PITCH]; // 33792 B bf16 L^T
    __shared__ __align__(16) char UN[17408];                  // E / scratch union
    __shared__ float bcxL[240];
    u32*   ESH  = (u32*)UN;
    float* scrF = (float*)UN;

    const int tid  = threadIdx.x;
    const int row  = blockIdx.x*TPB + tid;
    const bool active = row < B;
    const int lane = tid & 63;
    const int qq = lane >> 4, pp = lane & 15;
    const int wbase = tid & 192;       // wave index * 64

    // ---- staging: Bt (coalesced linear reads + LDS transpose writes), bcx ----
    for (int t = tid; t < 2048; t += TPB)          // cols 56..63, all k
        BtT[(56 + (t>>8))*BT_PITCH + (t&255)] = 0;
    for (int t = tid; t < 1024; t += TPB)          // all cols, k 240..255
        BtT[(t>>4)*BT_PITCH + 240 + (t&15)] = 0;
    for (int t = tid; t < 12480; t += TPB){        // lemb0: linear
        int k = t/52, c = t - k*52;
        BtT[c*BT_PITCH + k] = f2bf(lemb[t]);
    }
    for (int t = tid; t < 960; t += TPB){          // bcp: linear
        int k = t>>2, c = 52 + (t&3);
        BtT[c*BT_PITCH + k] = f2bf(bcp[t]);
    }
    for (int t = tid; t < 240; t += TPB) bcxL[t] = bcx[t];

    // ---- per-row inputs from phase A (issued before barrier) ----
    float qf[8];
    u32 iw0=0, iw1=0;
    if (active){
        const float* orow = out + (size_t)row*56;
        float4 q0 = *(const float4*)(orow+0);
        float4 q1 = *(const float4*)(orow+4);
        qf[0]=q0.x; qf[1]=q0.y; qf[2]=q0.z; qf[3]=q0.w;
        qf[4]=q1.x; qf[5]=q1.y; qf[6]=q1.z; qf[7]=q1.w;
        union{ float2 f; u32 u[2]; } iv;
        iv.f = *(const float2*)(orow+8);
        iw0 = iv.u[0]; iw1 = iv.u[1];
    } else {
        #pragma unroll
        for (int m=0;m<8;m++) qf[m]=0.f;
    }
    float decay = expf(glogdecay[0]);
    __syncthreads();

    // ---- Hadamard half-tables (16 regs; lo/hi recomputed per use) ----
    float s01[4], s23[4], s45[4], s67[4];
    {
        float a01p=qf[0]+qf[1], a01m=qf[0]-qf[1];
        float a23p=qf[2]+qf[3], a23m=qf[2]-qf[3];
        float a45p=qf[4]+qf[5], a45m=qf[4]-qf[5];
        float a67p=qf[6]+qf[7], a67m=qf[6]-qf[7];
        s01[0]=a01p; s01[1]=-a01m; s01[2]=a01m; s01[3]=-a01p;
        s23[0]=a23p; s23[1]=-a23m; s23[2]=a23m; s23[3]=-a23p;
        s45[0]=a45p; s45[1]=-a45m; s45[2]=a45m; s45[3]=-a45p;
        s67[0]=a67p; s67[1]=-a67m; s67[2]=a67m; s67[3]=-a67p;
    }

    // ---- chunked softmax-GEMM: E[64,240] x L[240,64] on MFMA ----
    f32x4 acc[4][4];
    #pragma unroll
    for (int s=0;s<4;s++)
        #pragma unroll
        for (int n=0;n<4;n++)
            acc[s][n] = f32x4{0.f,0.f,0.f,0.f};
    float den = 0.f;

    EP4(0,1,  0, 0) EP4(0,2,  4, 2) EP4(0,3,  8, 4) EP4(0,4, 12, 6)
    EP4(0,5, 16, 8) EP4(0,6, 20,10) EP4(0,7, 24,12) EP4(1,2, 28,14)
    EFLUSH(0)
    EP4(1,3, 32, 0) EP4(1,4, 36, 2) EP4(1,5, 40, 4) EP4(1,6, 44, 6)
    EP4(1,7, 48, 8) EP4(2,3, 52,10) EP4(2,4, 56,12) EP4(2,5, 60,14)
    EFLUSH(1)
    EP4(2,6, 64, 0) EP4(2,7, 68, 2) EP4(3,4, 72, 4) EP4(3,5, 76, 6)
    EP4(3,6, 80, 8) EP4(3,7, 84,10) EP4(4,5, 88,12) EP4(4,6, 92,14)
    EFLUSH(2)
    EP4(4,7, 96, 0) EP4(5,6,100, 2) EP4(5,7,104, 4) EP4(6,7,108, 6)
    EH8(0,112, 8, 0,3,5,6,9,10,12,15)
    EH8(1,120,12, 1,2,4,7,8,11,13,14)
    EFLUSH(3)
    EH8(2,128, 0, 1,2,4,7,8,11,13,14)
    EH8(3,136, 4, 0,3,5,6,9,10,12,15)
    EH8(4,144, 8, 1,2,4,7,8,11,13,14)
    EH8(5,152,12, 0,3,5,6,9,10,12,15)
    EFLUSH(4)
    EH8(6,160, 0, 0,3,5,6,9,10,12,15)
    EH8(7,168, 4, 1,2,4,7,8,11,13,14)
    EH8(8,176, 8, 1,2,4,7,8,11,13,14)
    EH8(9,184,12, 0,3,5,6,9,10,12,15)
    EFLUSH(5)
    EH8(10,192, 0, 0,3,5,6,9,10,12,15)
    EH8(11,200, 4, 1,2,4,7,8,11,13,14)
    EH8(12,208, 8, 0,3,5,6,9,10,12,15)
    EH8(13,216,12, 1,2,4,7,8,11,13,14)
    EFLUSH(6)
    EH8(14,224, 0, 1,2,4,7,8,11,13,14)
    EH8(15,232, 4, 0,3,5,6,9,10,12,15)
    #pragma unroll
    for (int w2=8; w2<16; w2++) ESH[w2*E_PITCH + tid]=0u;
    EFLUSH(7)

    __syncthreads();   // all waves' E reads done -> region reusable as scratch

    // ---- epilogue: transpose D back via per-wave scratch ----
    float emb[56];
    float* scr = scrF + (tid>>6)*(16*SCR_PITCH);
    #pragma unroll
    for (int s=0;s<4;s++){
        #pragma unroll
        for (int n=0;n<4;n++){
            #pragma unroll
            for (int r=0;r<4;r++)
                scr[(4*qq+r)*SCR_PITCH + 16*n + pp] = acc[s][n][r];
        }
        if ((lane>>4) == s){
            const float4* rp = (const float4*)(scr + pp*SCR_PITCH);
            #pragma unroll
            for (int t=0;t<14;t++){
                float4 v = rp[t];
                emb[4*t]=v.x; emb[4*t+1]=v.y; emb[4*t+2]=v.z; emb[4*t+3]=v.w;
            }
        }
    }

    if (active){
        float rden = 1.f/den;
        #pragma unroll
        for (int k=0;k<56;k++) emb[k] *= rden;

        int i1 = iw0 & 255, i2 = (iw0>>8)&255, i3 = (iw0>>16)&255, i4 = (iw0>>24)&255;
        int i5 = iw1 & 255, i6 = (iw1>>8)&255, i7 = (iw1>>16)&255;

        float dp = decay;
        #define DO_G2(LVL, IV) { \
            float ild = 1.0f/dp; \
            const float4* ep4 = (const float4*)(lemb + ((size_t)(LVL)*240 + (size_t)(IV))*52); \
            _Pragma("unroll") for (int t4=0;t4<13;t4++){ float4 v=ep4[t4]; \
                emb[4*t4+0]=fmaf(ild,v.x,emb[4*t4+0]); emb[4*t4+1]=fmaf(ild,v.y,emb[4*t4+1]); \
                emb[4*t4+2]=fmaf(ild,v.z,emb[4*t4+2]); emb[4*t4+3]=fmaf(ild,v.w,emb[4*t4+3]); } \
            float4 cv = *(const float4*)(rcpar + ((size_t)((LVL)-1)*240 + (size_t)(IV))*4); \
            emb[52]=fmaf(ild,cv.x,emb[52]); emb[53]=fmaf(ild,cv.y,emb[53]); \
            emb[54]=fmaf(ild,cv.z,emb[54]); emb[55]=fmaf(ild,cv.w,emb[55]); \
            dp *= decay; }
        DO_G2(1,i1) DO_G2(2,i2) DO_G2(3,i3) DO_G2(4,i4)
        DO_G2(5,i5) DO_G2(6,i6) DO_G2(7,i7)
        #undef DO_G2

        float4* o4 = (float4*)(out + (size_t)row*56);
        #pragma unroll
        for (int t=0;t<14;t++)
            o4[t] = make_float4(emb[4*t], emb[4*t+1], emb[4*t+2], emb[4*t+3]);
    }
}

// ============ K2: f64 rescue (pre-refine) ====================================
__global__ __launch_bounds__(RTPB) void e8_rescue(
    const float* __restrict__ g_obs,
    const float* __restrict__ pw1, const float* __restrict__ pb1,
    const float* __restrict__ pw2, const float* __restrict__ pb2,
    const float* __restrict__ lemb, const float* __restrict__ bcp,
    const float* __restrict__ rcpar, const float* __restrict__ bcx,
    const float* __restrict__ glogdecay,
    const u32* __restrict__ cnt, const u32* __restrict__ list,
    const unsigned char* __restrict__ flags, int useCompact,
    float* __restrict__ out, int B)
{
    __shared__ float L[LDSZ];
    __shared__ float Ttab[RTPB*25];
    const int tid = threadIdx.x;
    int row = -1;
    bool valid;
    if (useCompact){
        u32 c = *cnt;
        if ((u32)(blockIdx.x*RTPB) >= c) return;
        int gid = blockIdx.x*RTPB + tid;
        valid = (gid < (int)c);
        if (valid) row = (int)list[gid];
    } else {
        row = blockIdx.x*RTPB + tid;
        valid = (row < B) && (flags[row] != 0);
        if (!__syncthreads_or(valid ? 1 : 0)) return;
    }
    stageL(L, tid, RTPB, lemb, bcp, bcx);
    __syncthreads();
    if (!valid) return;

    double ob[14];
    #pragma unroll
    for (int j=0;j<14;j++) ob[j] = (double)g_obs[(size_t)row*14+j];
    double qa[8];
    #pragma unroll
    for (int m=0;m<8;m++) qa[m] = (double)pb2[m];
    #pragma unroll 1
    for (int k=0;k<32;k++){
        double a = (double)pb1[k];
        #pragma unroll
        for (int j=0;j<14;j++) a += (double)pw1[k*14+j]*ob[j];
        double hk = 0.5*a*(1.0 + erf(a*0.70710678118654752440));
        #pragma unroll
        for (int m=0;m<8;m++) qa[m] += (double)pw2[m*32+k]*hk;
    }
    double n2 = 0.0;
    #pragma unroll
    for (int m=0;m<8;m++) n2 += qa[m]*qa[m];
    double nr = sqrt(n2); if (nr < 1e-12) nr = 1e-12;
    double q[8], residual[8];
    #pragma unroll
    for (int m=0;m<8;m++){ q[m] = qa[m]/nr*1.4142135623730951; residual[m]=q[m]; }

    double decay_d = exp((double)glogdecay[0]);
    double dpow = 1.0;
    int idxs[8] = {0,0,0,0,0,0,0,0};
    #pragma unroll
    for (int lvl=0; lvl<8; ++lvl){
        double rs = 0.5*dpow;
        double x[8];
        #pragma unroll
        for (int k=0;k<8;k++) x[k]=residual[k]*rs;
        idxs[lvl] = scan_fast_f64(x, 2.0/dpow, residual);
        dpow *= decay_d;
    }
    float qf[8];
    #pragma unroll
    for (int m=0;m<8;m++) qf[m]=(float)q[m];
    phaseB(L, Ttab + tid*25, qf, idxs[1],idxs[2],idxs[3],idxs[4],idxs[5],idxs[6],idxs[7],
           (float)decay_d, lemb, rcpar, out + (size_t)row*56);
}

// ============ K3: gated refinement MLP (standalone, proven) ==================
__global__ __launch_bounds__(TPB) void e8_refine(
    const float* __restrict__ rw1, const float* __restrict__ rb1,
    const float* __restrict__ rw2, const float* __restrict__ rb2,
    const float* __restrict__ rgate,
    float* __restrict__ out, int B)
{
    __shared__ float W1[2704];
    __shared__ float W2T[2704];
    __shared__ float Bv[104];
    const int tid = threadIdx.x;
    for (int t = tid; t < 2704; t += TPB) W1[t] = rw1[t];
    for (int t = tid; t < 2704; t += TPB){
        int m = t/52, k = t - m*52;
        W2T[k*52 + m] = rw2[t];
    }
    for (int t = tid; t < 104; t += TPB) Bv[t] = (t < 52) ? rb1[t] : rb2[t-52];
    __syncthreads();

    const int row = blockIdx.x*TPB + tid;
    if (row >= B) return;
    float* orow = out + (size_t)row*56;
    float emb[52];
    {
        const float4* o4 = (const float4*)orow;
        #pragma unroll
        for (int t=0;t<13;t++){
            float4 v = o4[t];
            emb[4*t]=v.x; emb[4*t+1]=v.y; emb[4*t+2]=v.z; emb[4*t+3]=v.w;
        }
    }
    float sg = 1.f/(1.f+__expf(-rgate[0]));
    float acc[52];
    #pragma unroll
    for (int m=0;m<52;m++) acc[m]=0.f;
    #pragma unroll 1
    for (int k=0;k<52;k++){
        const float4* w1 = (const float4*)(W1 + k*52);
        float a0=0.f,a1=0.f,a2=0.f,a3=0.f;
        #pragma unroll
        for (int t=0;t<13;t++){
            float4 w = w1[t];
            a0=fmaf(w.x,emb[4*t+0],a0); a1=fmaf(w.y,emb[4*t+1],a1);
            a2=fmaf(w.z,emb[4*t+2],a2); a3=fmaf(w.w,emb[4*t+3],a3);
        }
        float a = ((a0+a1)+(a2+a3)) + Bv[k];
        float gk = sg*0.5f*a*(1.f+erff(a*0.70710678f));
        const float4* w2 = (const float4*)(W2T + k*52);
        #pragma unroll
        for (int t=0;t<13;t++){
            float4 w = w2[t];
            acc[4*t+0]=fmaf(gk,w.x,acc[4*t+0]); acc[4*t+1]=fmaf(gk,w.y,acc[4*t+1]);
            acc[4*t+2]=fmaf(gk,w.z,acc[4*t+2]); acc[4*t+3]=fmaf(gk,w.w,acc[4*t+3]);
        }
    }
    float4* o4 = (float4*)orow;
    #pragma unroll
    for (int t=0;t<13;t++){
        float4 v;
        v.x = emb[4*t+0] + fmaf(sg, Bv[52+4*t+0], acc[4*t+0]);
        v.y = emb[4*t+1] + fmaf(sg, Bv[52+4*t+1], acc[4*t+1]);
        v.z = emb[4*t+2] + fmaf(sg, Bv[52+4*t+2], acc[4*t+2]);
        v.w = emb[4*t+3] + fmaf(sg, Bv[52+4*t+3], acc[4*t+3]);
        o4[t] = v;
    }
}

extern "C" void kernel_launch(void* const* d_in, const int* in_sizes, int n_in,
                              void* d_out, int out_size, void* d_ws, size_t ws_size,
                              hipStream_t stream)
{
    const float* obs  = (const float*)d_in[0];
    const float* pw1  = (const float*)d_in[1];
    const float* pb1  = (const float*)d_in[2];
    const float* pw2  = (const float*)d_in[3];
    const float* pb2  = (const float*)d_in[4];
    const float* lemb = (const float*)d_in[5];
    const float* bcp  = (const float*)d_in[6];
    const float* rcp  = (const float*)d_in[7];
    const float* bcx  = (const float*)d_in[8];
    const float* ld   = (const float*)d_in[9];
    const float* rw1  = (const float*)d_in[10];
    const float* rb1  = (const float*)d_in[11];
    const float* rw2  = (const float*)d_in[12];
    const float* rb2  = (const float*)d_in[13];
    const float* rg   = (const float*)d_in[14];

    int B = in_sizes[0] / 14;
    int grid  = (B + TPB - 1) / TPB;
    int rgrid = (B + RTPB - 1) / RTPB;

    bool compact = ws_size >= (size_t)256 + (size_t)B*4;
    u32* cnt  = (u32*)d_ws;
    u32* list = (u32*)d_ws + 64;
    unsigned char* flags = (unsigned char*)d_ws + 256;

    hipMemsetAsync(d_ws, 0, 8, stream);

    e8_phaseA<<<grid, TPB, 0, stream>>>(obs, pw1, pb1, pw2, pb2, ld,
                                        cnt, list, flags, compact?1:0, (float*)d_out, B);
    e8_phaseB<<<grid, TPB, 0, stream>>>(lemb, bcp, rcp, bcx, ld, (float*)d_out, B);
    e8_rescue<<<rgrid, RTPB, 0, stream>>>(obs, pw1, pb1, pw2, pb2, lemb, bcp, rcp, bcx, ld,
                                          cnt, list, flags, compact?1:0, (float*)d_out, B);
    e8_refine<<<grid, TPB, 0, stream>>>(rw1, rb1, rw2, rb2, rg, (float*)d_out, B);
}